// Round 1
// baseline (515.636 us; speedup 1.0000x reference)
//
#include <hip/hip_runtime.h>

// ---- problem constants ----
#define B_    2
#define S_    1024
#define DM_   2048
#define H_    16
#define HD_   128
#define RD_   64
#define DQL_  384
#define DKVL_ 512
#define NTOK  (B_*S_)       // 2048 tokens
#define CATD  (HD_+RD_)     // 192 = concat(head, rope) dims

typedef float f32x4 __attribute__((ext_vector_type(4)));
typedef short s16x8 __attribute__((ext_vector_type(8)));   // 8 bf16 in 4 VGPRs

__device__ __forceinline__ unsigned short f2b(float f) {   // fp32 -> bf16 RNE
  unsigned u = __float_as_uint(f);
  u = (u + 0x7FFFu + ((u >> 16) & 1u)) >> 16;
  return (unsigned short)u;
}

__device__ __forceinline__ f32x4 mfma16(s16x8 a, s16x8 b, f32x4 c) {
  return __builtin_amdgcn_mfma_f32_16x16x32_bf16(a, b, c, 0, 0, 0);
}

// ---------------- fp32 -> bf16 elementwise (x) ----------------
__global__ __launch_bounds__(256) void k_f2b(const float* __restrict__ in,
                                             unsigned short* __restrict__ out, int n4) {
  int i = blockIdx.x * 256 + threadIdx.x;
  if (i >= n4) return;
  const float4 v = reinterpret_cast<const float4*>(in)[i];
  ushort4 o;
  o.x = f2b(v.x); o.y = f2b(v.y); o.z = f2b(v.z); o.w = f2b(v.w);
  reinterpret_cast<ushort4*>(out)[i] = o;
}

// ---------------- fp32 (R x C) -> bf16 transposed (C x R) ----------------
__global__ __launch_bounds__(256) void k_transpose_b(const float* __restrict__ in,
                                                     unsigned short* __restrict__ out,
                                                     int R, int C) {
  __shared__ float tile[64][65];
  const int r0 = blockIdx.x * 64, c0 = blockIdx.y * 64;
  const int t = threadIdx.x;
  const int tr = t >> 4, tc4 = (t & 15) * 4;
#pragma unroll
  for (int i = 0; i < 4; ++i) {
    const int rr = tr + i * 16;
    const float4 v = *reinterpret_cast<const float4*>(in + (size_t)(r0 + rr) * C + c0 + tc4);
    tile[rr][tc4 + 0] = v.x; tile[rr][tc4 + 1] = v.y;
    tile[rr][tc4 + 2] = v.z; tile[rr][tc4 + 3] = v.w;
  }
  __syncthreads();
#pragma unroll
  for (int i = 0; i < 4; ++i) {
    const int oc = tr + i * 16;            // output row = original column
    ushort4 o;
    o.x = f2b(tile[tc4 + 0][oc]); o.y = f2b(tile[tc4 + 1][oc]);
    o.z = f2b(tile[tc4 + 2][oc]); o.w = f2b(tile[tc4 + 3][oc]);
    *reinterpret_cast<ushort4*>(out + (size_t)(c0 + oc) * R + r0 + tc4) = o;
  }
}

// ---------------- generic bf16 GEMM: C(MxN,fp32) = A(MxK) @ Bt(NxK)^T ----------------
// M,N multiples of 128; K multiple of 32.
#define GLDS 40   // padded LDS row stride (32 + 8) -> 2-way bank aliasing (free)
__global__ __launch_bounds__(256) void k_gemm(const unsigned short* __restrict__ A,
                                              const unsigned short* __restrict__ Bt,
                                              float* __restrict__ C,
                                              int M, int N, int K) {
  __shared__ unsigned short As[128 * GLDS];
  __shared__ unsigned short Bs[128 * GLDS];
  const int tm = blockIdx.x * 128;
  const int tn = blockIdx.y * 128;
  const int tid = threadIdx.x;
  const int wave = tid >> 6, lane = tid & 63;
  const int wr = (wave >> 1) * 64, wc = (wave & 1) * 64;   // 2x2 waves of 64x64
  const int l16 = lane & 15, kg = lane >> 4;

  f32x4 acc[4][4] = {};

  const unsigned short* Ag = A + (size_t)tm * K;
  const unsigned short* Bg = Bt + (size_t)tn * K;
  const int row0 = tid >> 2, c8 = (tid & 3) * 8;   // 8-elem staging slots

  for (int k0 = 0; k0 < K; k0 += 32) {
    __syncthreads();
#pragma unroll
    for (int r = 0; r < 2; ++r) {
      const int row = row0 + r * 64;
      s16x8 av = *reinterpret_cast<const s16x8*>(Ag + (size_t)row * K + k0 + c8);
      *reinterpret_cast<s16x8*>(&As[row * GLDS + c8]) = av;
      s16x8 bv = *reinterpret_cast<const s16x8*>(Bg + (size_t)row * K + k0 + c8);
      *reinterpret_cast<s16x8*>(&Bs[row * GLDS + c8]) = bv;
    }
    __syncthreads();
    s16x8 af[4], bfr[4];
#pragma unroll
    for (int i = 0; i < 4; ++i)
      af[i] = *reinterpret_cast<const s16x8*>(&As[(wr + i * 16 + l16) * GLDS + kg * 8]);
#pragma unroll
    for (int i = 0; i < 4; ++i)
      bfr[i] = *reinterpret_cast<const s16x8*>(&Bs[(wc + i * 16 + l16) * GLDS + kg * 8]);
#pragma unroll
    for (int mi = 0; mi < 4; ++mi)
#pragma unroll
      for (int ni = 0; ni < 4; ++ni)
        acc[mi][ni] = mfma16(af[mi], bfr[ni], acc[mi][ni]);
  }

#pragma unroll
  for (int mi = 0; mi < 4; ++mi)
#pragma unroll
    for (int ni = 0; ni < 4; ++ni) {
      const int r0 = tm + wr + mi * 16 + kg * 4;     // C layout: row=(lane>>4)*4+j
      const int c  = tn + wc + ni * 16 + l16;        //           col=lane&15
#pragma unroll
      for (int j = 0; j < 4; ++j)
        C[(size_t)(r0 + j) * N + c] = acc[mi][ni][j];
    }
}

// ---------------- RMSNorm row-wise, fp32 in -> bf16 out ----------------
__global__ __launch_bounds__(64) void k_rmsnorm(const float* __restrict__ in,
                                                const float* __restrict__ w,
                                                unsigned short* __restrict__ out, int D) {
  const int row = blockIdx.x;
  const float* x = in + (size_t)row * D;
  float ss = 0.f;
  for (int i = threadIdx.x; i < D; i += 64) { const float v = x[i]; ss = fmaf(v, v, ss); }
#pragma unroll
  for (int off = 32; off; off >>= 1) ss += __shfl_xor(ss, off, 64);
  const float r = rsqrtf(ss / (float)D + 1e-6f);
  for (int i = threadIdx.x; i < D; i += 64)
    out[(size_t)row * D + i] = f2b(x[i] * r * w[i]);
}

// ---------------- build concat(Q|rope(Qr)) in [B*H][S][192] bf16 ----------------
__global__ __launch_bounds__(256) void k_build_cat(const float* __restrict__ up_raw,   // [NTOK][2048]
                                                   const float* __restrict__ rope_raw, // [NTOK][1024]
                                                   unsigned short* __restrict__ cat) { // [B*H][S][192]
  const int bs = blockIdx.x;               // b*S + s
  const int b = bs >> 10, s = bs & 1023;
  const int t = threadIdx.x;
  for (int e = t; e < 2048; e += 256) {
    const int h = e >> 7, d = e & 127;
    cat[((size_t)(b * H_ + h) * S_ + s) * CATD + d] = f2b(up_raw[(size_t)bs * 2048 + e]);
  }
  for (int pp = t; pp < 512; pp += 256) {  // 16 heads * 32 rope pairs
    const int h = pp >> 5, p = pp & 31;
    const float xe = rope_raw[(size_t)bs * 1024 + h * 64 + 2 * p];
    const float xo = rope_raw[(size_t)bs * 1024 + h * 64 + 2 * p + 1];
    const float freq = powf(10000.0f, -(float)(2 * p) / 64.0f);
    const float ang = (float)s * freq;
    float sn, cs;
    sincosf(ang, &sn, &cs);
    unsigned short* o = &cat[((size_t)(b * H_ + h) * S_ + s) * CATD + HD_ + 2 * p];
    o[0] = f2b(xe * cs - xo * sn);
    o[1] = f2b(xe * sn + xo * cs);
  }
}

// ---------------- pack V transposed: [B*H][HD][S] bf16 ----------------
__global__ __launch_bounds__(256) void k_pack_vt(const float* __restrict__ v_raw,     // [NTOK][2048]
                                                 unsigned short* __restrict__ VT) {
  __shared__ float tile[64][65];
  const int bh = blockIdx.x;
  const int s0 = blockIdx.y * 64, d0 = blockIdx.z * 64;
  const int b = bh >> 4, h = bh & 15;
  const int t = threadIdx.x;
  const int tr = t >> 4, tc4 = (t & 15) * 4;
#pragma unroll
  for (int i = 0; i < 4; ++i) {
    const int sr = tr + i * 16;
    const float4 v = *reinterpret_cast<const float4*>(
        v_raw + (size_t)(b * S_ + s0 + sr) * 2048 + h * HD_ + d0 + tc4);
    tile[sr][tc4 + 0] = v.x; tile[sr][tc4 + 1] = v.y;
    tile[sr][tc4 + 2] = v.z; tile[sr][tc4 + 3] = v.w;
  }
  __syncthreads();
#pragma unroll
  for (int i = 0; i < 4; ++i) {
    const int dr = tr + i * 16;
    ushort4 o;
    o.x = f2b(tile[tc4 + 0][dr]); o.y = f2b(tile[tc4 + 1][dr]);
    o.z = f2b(tile[tc4 + 2][dr]); o.w = f2b(tile[tc4 + 3][dr]);
    *reinterpret_cast<ushort4*>(VT + ((size_t)bh * HD_ + d0 + dr) * S_ + s0 + tc4) = o;
  }
}

// ---------------- attention: scores -> softmax -> attn out + P@V ----------------
// One block = 32 q-rows of one (b,h). 512 threads = 8 waves. LDS = 32x1032 fp32.
#define SST 1032
__global__ __launch_bounds__(512) void k_attn(const unsigned short* __restrict__ Qcat,
                                              const unsigned short* __restrict__ Kcat,
                                              const unsigned short* __restrict__ VT,
                                              float* __restrict__ attn_out,
                                              unsigned short* __restrict__ ctx) {
  __shared__ float P[32 * SST];
  const int blk = blockIdx.x;
  const int bh = blk >> 5;
  const int q0 = (blk & 31) * 32;
  const int b = bh >> 4, h = bh & 15;
  const int tid = threadIdx.x;
  const int wave = tid >> 6, lane = tid & 63;
  const int l16 = lane & 15, kg = lane >> 4;

  // ---- scores: wave covers key-cols [wave*128, +128) ----
  const unsigned short* Qb = Qcat + ((size_t)bh * S_ + q0) * CATD;
  const unsigned short* Kb = Kcat + (size_t)bh * S_ * CATD;
  s16x8 qf[2][6];
#pragma unroll
  for (int mi = 0; mi < 2; ++mi)
#pragma unroll
    for (int ks = 0; ks < 6; ++ks)
      qf[mi][ks] = *reinterpret_cast<const s16x8*>(
          Qb + (size_t)(mi * 16 + l16) * CATD + ks * 32 + kg * 8);

  const int cw = wave * 128;
  f32x4 acc[2][8] = {};
#pragma unroll
  for (int ni = 0; ni < 8; ++ni) {
    const unsigned short* Kn = Kb + (size_t)(cw + ni * 16 + l16) * CATD + kg * 8;
#pragma unroll
    for (int ks = 0; ks < 6; ++ks) {
      const s16x8 kf = *reinterpret_cast<const s16x8*>(Kn + ks * 32);
      acc[0][ni] = mfma16(qf[0][ks], kf, acc[0][ni]);
      acc[1][ni] = mfma16(qf[1][ks], kf, acc[1][ni]);
    }
  }
  const float scale = 0.07216878364870323f;   // (HD+RD)^-0.5 = 192^-0.5
#pragma unroll
  for (int mi = 0; mi < 2; ++mi)
#pragma unroll
    for (int ni = 0; ni < 8; ++ni) {
      const int row = mi * 16 + kg * 4;
      const int col = cw + ni * 16 + l16;
#pragma unroll
      for (int j = 0; j < 4; ++j)
        P[(row + j) * SST + col] = acc[mi][ni][j] * scale;
    }
  __syncthreads();

  // ---- softmax per row (16 threads/row, groups aligned to lane>>4) ----
  {
    const int r = tid >> 4, li = tid & 15;
    float* Pr = P + r * SST;
    float m = -1e30f;
    for (int i = li; i < S_; i += 16) m = fmaxf(m, Pr[i]);
#pragma unroll
    for (int off = 8; off; off >>= 1) m = fmaxf(m, __shfl_xor(m, off, 16));
    float sum = 0.f;
    for (int i = li; i < S_; i += 16) sum += expf(Pr[i] - m);
#pragma unroll
    for (int off = 8; off; off >>= 1) sum += __shfl_xor(sum, off, 16);
    const float rl = 1.0f / sum;
    float* Ao = attn_out + ((size_t)bh * S_ + q0 + r) * S_;
    for (int i = li; i < S_; i += 16) {
      const float p = expf(Pr[i] - m) * rl;
      Pr[i] = p;
      Ao[i] = p;
    }
  }
  __syncthreads();

  // ---- P @ V: wave covers dims [wave*16, +16) ----
  const unsigned short* Vb = VT + (size_t)bh * HD_ * S_ + (size_t)(wave * 16 + l16) * S_ + kg * 8;
  f32x4 oacc[2] = {};
  for (int kt = 0; kt < 32; ++kt) {
    const s16x8 vf = *reinterpret_cast<const s16x8*>(Vb + kt * 32);
#pragma unroll
    for (int mi = 0; mi < 2; ++mi) {
      const float* Pp = P + (mi * 16 + l16) * SST + kt * 32 + kg * 8;
      s16x8 af;
#pragma unroll
      for (int j = 0; j < 8; ++j) af[j] = (short)f2b(Pp[j]);
      oacc[mi] = mfma16(af, vf, oacc[mi]);
    }
  }
#pragma unroll
  for (int mi = 0; mi < 2; ++mi) {
    const int row = mi * 16 + kg * 4;
    const int col = wave * 16 + l16;
#pragma unroll
    for (int j = 0; j < 4; ++j) {
      const int q = q0 + row + j;
      ctx[((size_t)(b * S_ + q)) * 2048 + h * HD_ + col] = f2b(oacc[mi][j]);
    }
  }
}

// ---------------- host launch ----------------
extern "C" void kernel_launch(void* const* d_in, const int* in_sizes, int n_in,
                              void* d_out, int out_size, void* d_ws, size_t ws_size,
                              hipStream_t stream) {
  const float* x         = (const float*)d_in[0];
  const float* Wq_down   = (const float*)d_in[1];
  const float* q_norm_w  = (const float*)d_in[2];
  const float* Wq_up     = (const float*)d_in[3];
  const float* Wq_rope   = (const float*)d_in[4];
  const float* Wkv_down  = (const float*)d_in[5];
  const float* kv_norm_w = (const float*)d_in[6];
  const float* Wk_up     = (const float*)d_in[7];
  const float* Wv_up     = (const float*)d_in[8];
  const float* Wk_rope   = (const float*)d_in[9];
  const float* Wout      = (const float*)d_in[10];

  float* out0 = (float*)d_out;                        // [B,S,DM]
  float* attn = out0 + (size_t)B_ * S_ * DM_;         // [B,H,S,S]

  char* ws = (char*)d_ws;
  size_t off = 0;
  auto alloc = [&](size_t bytes) -> void* {
    void* p = ws + off;
    off += (bytes + 255) & ~(size_t)255;
    return p;
  };

  unsigned short* xb    = (unsigned short*)alloc((size_t)NTOK * DM_ * 2);
  unsigned short* WqdT  = (unsigned short*)alloc((size_t)DQL_ * DM_ * 2);
  unsigned short* WqupT = (unsigned short*)alloc((size_t)(H_*HD_) * DQL_ * 2);
  unsigned short* WqrT  = (unsigned short*)alloc((size_t)(H_*RD_) * DM_ * 2);
  unsigned short* WkvdT = (unsigned short*)alloc((size_t)DKVL_ * DM_ * 2);
  unsigned short* WkupT = (unsigned short*)alloc((size_t)(H_*HD_) * DKVL_ * 2);
  unsigned short* WvupT = (unsigned short*)alloc((size_t)(H_*HD_) * DKVL_ * 2);
  unsigned short* WkrT  = (unsigned short*)alloc((size_t)(H_*RD_) * DM_ * 2);
  unsigned short* WoutT = (unsigned short*)alloc((size_t)DM_ * DM_ * 2);
  float* cq_raw         = (float*)alloc((size_t)NTOK * DQL_ * 4);
  unsigned short* cqb   = (unsigned short*)alloc((size_t)NTOK * DQL_ * 2);
  float* ckv_raw        = (float*)alloc((size_t)NTOK * DKVL_ * 4);
  unsigned short* ckvb  = (unsigned short*)alloc((size_t)NTOK * DKVL_ * 2);
  float* rope_raw       = (float*)alloc((size_t)NTOK * H_ * RD_ * 4);
  float* big_raw        = (float*)alloc((size_t)NTOK * DM_ * 4);
  unsigned short* Qcat  = (unsigned short*)alloc((size_t)B_*H_*S_ * CATD * 2);
  unsigned short* Kcat  = (unsigned short*)alloc((size_t)B_*H_*S_ * CATD * 2);
  unsigned short* VTb   = (unsigned short*)alloc((size_t)B_*H_*HD_ * S_ * 2);
  unsigned short* ctxb  = (unsigned short*)alloc((size_t)NTOK * DM_ * 2);

  if (off > ws_size) return;   // workspace too small: fail validation cleanly

  // 1. converts / weight transposes
  k_f2b<<<(NTOK * DM_ / 4 + 255) / 256, 256, 0, stream>>>(x, xb, NTOK * DM_ / 4);
  k_transpose_b<<<dim3(DM_/64, DQL_/64),       256, 0, stream>>>(Wq_down,  WqdT,  DM_,  DQL_);
  k_transpose_b<<<dim3(DQL_/64, (H_*HD_)/64),  256, 0, stream>>>(Wq_up,    WqupT, DQL_, H_*HD_);
  k_transpose_b<<<dim3(DM_/64, (H_*RD_)/64),   256, 0, stream>>>(Wq_rope,  WqrT,  DM_,  H_*RD_);
  k_transpose_b<<<dim3(DM_/64, DKVL_/64),      256, 0, stream>>>(Wkv_down, WkvdT, DM_,  DKVL_);
  k_transpose_b<<<dim3(DKVL_/64, (H_*HD_)/64), 256, 0, stream>>>(Wk_up,    WkupT, DKVL_, H_*HD_);
  k_transpose_b<<<dim3(DKVL_/64, (H_*HD_)/64), 256, 0, stream>>>(Wv_up,    WvupT, DKVL_, H_*HD_);
  k_transpose_b<<<dim3(DM_/64, (H_*RD_)/64),   256, 0, stream>>>(Wk_rope,  WkrT,  DM_,  H_*RD_);
  k_transpose_b<<<dim3(DM_/64, DM_/64),        256, 0, stream>>>(Wout,     WoutT, DM_,  DM_);

  // 2. down-projections + RMSNorm
  k_gemm<<<dim3(NTOK/128, DQL_/128),  256, 0, stream>>>(xb, WqdT,  cq_raw,  NTOK, DQL_,  DM_);
  k_rmsnorm<<<NTOK, 64, 0, stream>>>(cq_raw,  q_norm_w,  cqb,  DQL_);
  k_gemm<<<dim3(NTOK/128, DKVL_/128), 256, 0, stream>>>(xb, WkvdT, ckv_raw, NTOK, DKVL_, DM_);
  k_rmsnorm<<<NTOK, 64, 0, stream>>>(ckv_raw, kv_norm_w, ckvb, DKVL_);

  // 3. Q path
  k_gemm<<<dim3(NTOK/128, DM_/128),      256, 0, stream>>>(cqb, WqupT, big_raw,  NTOK, H_*HD_, DQL_);
  k_gemm<<<dim3(NTOK/128, (H_*RD_)/128), 256, 0, stream>>>(xb,  WqrT,  rope_raw, NTOK, H_*RD_, DM_);
  k_build_cat<<<NTOK, 256, 0, stream>>>(big_raw, rope_raw, Qcat);

  // 4. K path (reuse big_raw / rope_raw)
  k_gemm<<<dim3(NTOK/128, DM_/128),      256, 0, stream>>>(ckvb, WkupT, big_raw,  NTOK, H_*HD_, DKVL_);
  k_gemm<<<dim3(NTOK/128, (H_*RD_)/128), 256, 0, stream>>>(xb,   WkrT,  rope_raw, NTOK, H_*RD_, DM_);
  k_build_cat<<<NTOK, 256, 0, stream>>>(big_raw, rope_raw, Kcat);

  // 5. V path (reuse big_raw)
  k_gemm<<<dim3(NTOK/128, DM_/128), 256, 0, stream>>>(ckvb, WvupT, big_raw, NTOK, H_*HD_, DKVL_);
  k_pack_vt<<<dim3(B_*H_, S_/64, HD_/64), 256, 0, stream>>>(big_raw, VTb);

  // 6. attention (writes attn output + bf16 context)
  k_attn<<<B_*H_*(S_/32), 512, 0, stream>>>(Qcat, Kcat, VTb, attn, ctxb);

  // 7. output projection -> out0
  k_gemm<<<dim3(NTOK/128, DM_/128), 256, 0, stream>>>(ctxb, WoutT, out0, NTOK, DM_, DM_);
}

// Round 2
// 404.024 us; speedup vs baseline: 1.2763x; 1.2763x over previous
//
#include <hip/hip_runtime.h>

#define B_    2
#define S_    1024
#define DM_   2048
#define H_    16
#define HD_   128
#define RD_   64
#define DQL_  384
#define DKVL_ 512
#define NTOK  (B_*S_)
#define CATD  (HD_+RD_)

typedef float f32x4 __attribute__((ext_vector_type(4)));
typedef short s16x8 __attribute__((ext_vector_type(8)));
typedef unsigned int u32;

__device__ __forceinline__ unsigned short f2b(float f) {   // fp32 -> bf16 RNE
  u32 u = __float_as_uint(f);
  u = (u + 0x7FFFu + ((u >> 16) & 1u)) >> 16;
  return (unsigned short)u;
}
__device__ __forceinline__ f32x4 mfma16(s16x8 a, s16x8 b, f32x4 c) {
  return __builtin_amdgcn_mfma_f32_16x16x32_bf16(a, b, c, 0, 0, 0);
}
__device__ __forceinline__ void gl_lds16(const void* g, void* l) {
  __builtin_amdgcn_global_load_lds((const __attribute__((address_space(1))) u32*)g,
                                   (__attribute__((address_space(3))) u32*)l, 16, 0, 0);
}
__device__ __forceinline__ s16x8 pk8(float4 a, float4 b) {
  s16x8 r;
  r[0]=(short)f2b(a.x); r[1]=(short)f2b(a.y); r[2]=(short)f2b(a.z); r[3]=(short)f2b(a.w);
  r[4]=(short)f2b(b.x); r[5]=(short)f2b(b.y); r[6]=(short)f2b(b.z); r[7]=(short)f2b(b.w);
  return r;
}

// ---------------- fp32 -> bf16 elementwise ----------------
__global__ __launch_bounds__(256) void k_f2b(const float* __restrict__ in,
                                             unsigned short* __restrict__ out, int n4) {
  int i = blockIdx.x * 256 + threadIdx.x;
  if (i >= n4) return;
  const float4 v = reinterpret_cast<const float4*>(in)[i];
  ushort4 o;
  o.x = f2b(v.x); o.y = f2b(v.y); o.z = f2b(v.z); o.w = f2b(v.w);
  reinterpret_cast<ushort4*>(out)[i] = o;
}

// ---------------- fp32 (R x C) -> bf16 transposed (C x R) ----------------
__global__ __launch_bounds__(256) void k_transpose_b(const float* __restrict__ in,
                                                     unsigned short* __restrict__ out,
                                                     int R, int C) {
  __shared__ float tile[64][65];
  const int r0 = blockIdx.x * 64, c0 = blockIdx.y * 64;
  const int t = threadIdx.x;
  const int tr = t >> 4, tc4 = (t & 15) * 4;
#pragma unroll
  for (int i = 0; i < 4; ++i) {
    const int rr = tr + i * 16;
    const float4 v = *reinterpret_cast<const float4*>(in + (size_t)(r0 + rr) * C + c0 + tc4);
    tile[rr][tc4 + 0] = v.x; tile[rr][tc4 + 1] = v.y;
    tile[rr][tc4 + 2] = v.z; tile[rr][tc4 + 3] = v.w;
  }
  __syncthreads();
#pragma unroll
  for (int i = 0; i < 4; ++i) {
    const int oc = tr + i * 16;
    ushort4 o;
    o.x = f2b(tile[tc4 + 0][oc]); o.y = f2b(tile[tc4 + 1][oc]);
    o.z = f2b(tile[tc4 + 2][oc]); o.w = f2b(tile[tc4 + 3][oc]);
    *reinterpret_cast<ushort4*>(out + (size_t)(c0 + oc) * R + r0 + tc4) = o;
  }
}

// ---------------- bf16 GEMM, m97 structure: C(MxN,f32) = A(MxK) @ Bt(NxK)^T ----
// 128x128 tile, BK=32, linear LDS, global_load_lds width-16, 2-barrier loop.
__global__ __launch_bounds__(256) void k_gemm(const unsigned short* __restrict__ A,
                                              const unsigned short* __restrict__ Bt,
                                              float* __restrict__ C,
                                              int M, int N, int K) {
  __shared__ unsigned short As[128 * 32];
  __shared__ unsigned short Bs[128 * 32];
  // XCD-aware swizzle (all grids are multiples of 8 blocks)
  const int nwg = gridDim.x * gridDim.y;
  int id = blockIdx.y * gridDim.x + blockIdx.x;
  id = (id & 7) * (nwg >> 3) + (id >> 3);
  const int tm = (id % gridDim.x) * 128;
  const int tn = (id / gridDim.x) * 128;

  const int tid = threadIdx.x;
  const int wave = tid >> 6, lane = tid & 63;
  const int wr = (wave >> 1) * 64, wc = (wave & 1) * 64;
  const int l16 = lane & 15, kg = lane >> 4;
  const int r0s = tid >> 2, c0s = (tid & 3) * 8;   // staging: 16B per thread per issue

  const unsigned short* Ag = A + (size_t)tm * K;
  const unsigned short* Bg = Bt + (size_t)tn * K;
  f32x4 acc[4][4] = {};

  for (int k0 = 0; k0 < K; k0 += 32) {
    __syncthreads();
    gl_lds16(Ag + (size_t)r0s * K + k0 + c0s,        (void*)&As[tid * 8]);
    gl_lds16(Ag + (size_t)(r0s + 64) * K + k0 + c0s, (void*)&As[(tid + 256) * 8]);
    gl_lds16(Bg + (size_t)r0s * K + k0 + c0s,        (void*)&Bs[tid * 8]);
    gl_lds16(Bg + (size_t)(r0s + 64) * K + k0 + c0s, (void*)&Bs[(tid + 256) * 8]);
    __syncthreads();
    s16x8 af[4], bf4[4];
#pragma unroll
    for (int i = 0; i < 4; ++i)
      af[i] = *reinterpret_cast<const s16x8*>(&As[(wr + i * 16 + l16) * 32 + kg * 8]);
#pragma unroll
    for (int i = 0; i < 4; ++i)
      bf4[i] = *reinterpret_cast<const s16x8*>(&Bs[(wc + i * 16 + l16) * 32 + kg * 8]);
#pragma unroll
    for (int mi = 0; mi < 4; ++mi)
#pragma unroll
      for (int ni = 0; ni < 4; ++ni)
        acc[mi][ni] = mfma16(af[mi], bf4[ni], acc[mi][ni]);
  }

#pragma unroll
  for (int mi = 0; mi < 4; ++mi)
#pragma unroll
    for (int ni = 0; ni < 4; ++ni) {
      const int rr = tm + wr + mi * 16 + kg * 4;
      const int cc = tn + wc + ni * 16 + l16;
#pragma unroll
      for (int j = 0; j < 4; ++j)
        C[(size_t)(rr + j) * N + cc] = acc[mi][ni][j];
    }
}

// ---------------- RMSNorm (strided input) ----------------
__global__ __launch_bounds__(64) void k_rmsnorm(const float* __restrict__ in, int stride,
                                                const float* __restrict__ w,
                                                unsigned short* __restrict__ out, int D) {
  const int row = blockIdx.x;
  const float* x = in + (size_t)row * stride;
  float ss = 0.f;
  for (int i = threadIdx.x; i < D; i += 64) { const float v = x[i]; ss = fmaf(v, v, ss); }
#pragma unroll
  for (int off = 32; off; off >>= 1) ss += __shfl_xor(ss, off, 64);
  const float r = rsqrtf(ss / (float)D + 1e-6f);
  for (int i = threadIdx.x; i < D; i += 64)
    out[(size_t)row * D + i] = f2b(x[i] * r * w[i]);
}

// ---------------- build concat(up | rope) -> [B*H][S][192] bf16 ----------------
__global__ __launch_bounds__(256) void k_build_cat(const float* __restrict__ up, int ustride,
                                                   const float* __restrict__ rope, int rstride,
                                                   unsigned short* __restrict__ cat) {
  const int bs = blockIdx.x;
  const int b = bs >> 10, s = bs & 1023;
  const int t = threadIdx.x;
  for (int e = t; e < 2048; e += 256) {
    const int h = e >> 7, d = e & 127;
    cat[((size_t)(b * H_ + h) * S_ + s) * CATD + d] = f2b(up[(size_t)bs * ustride + e]);
  }
  for (int pp = t; pp < 512; pp += 256) {
    const int h = pp >> 5, p = pp & 31;
    const float xe = rope[(size_t)bs * rstride + h * 64 + 2 * p];
    const float xo = rope[(size_t)bs * rstride + h * 64 + 2 * p + 1];
    const float freq = powf(10000.0f, -(float)(2 * p) / 64.0f);
    const float ang = (float)s * freq;
    float sn, cs;
    sincosf(ang, &sn, &cs);
    unsigned short* o = &cat[((size_t)(b * H_ + h) * S_ + s) * CATD + HD_ + 2 * p];
    o[0] = f2b(xe * cs - xo * sn);
    o[1] = f2b(xe * sn + xo * cs);
  }
}

// ---------------- pack V transposed: [B*H][HD][S] bf16 (strided input) ----------
__global__ __launch_bounds__(256) void k_pack_vt(const float* __restrict__ v, int vstride,
                                                 unsigned short* __restrict__ VT) {
  __shared__ float tile[64][65];
  const int bh = blockIdx.x;
  const int s0 = blockIdx.y * 64, d0 = blockIdx.z * 64;
  const int b = bh >> 4, h = bh & 15;
  const int t = threadIdx.x;
  const int tr = t >> 4, tc4 = (t & 15) * 4;
#pragma unroll
  for (int i = 0; i < 4; ++i) {
    const int sr = tr + i * 16;
    const float4 vv = *reinterpret_cast<const float4*>(
        v + (size_t)(b * S_ + s0 + sr) * vstride + h * HD_ + d0 + tc4);
    tile[sr][tc4 + 0] = vv.x; tile[sr][tc4 + 1] = vv.y;
    tile[sr][tc4 + 2] = vv.z; tile[sr][tc4 + 3] = vv.w;
  }
  __syncthreads();
#pragma unroll
  for (int i = 0; i < 4; ++i) {
    const int dr = tr + i * 16;
    ushort4 o;
    o.x = f2b(tile[tc4 + 0][dr]); o.y = f2b(tile[tc4 + 1][dr]);
    o.z = f2b(tile[tc4 + 2][dr]); o.w = f2b(tile[tc4 + 3][dr]);
    *reinterpret_cast<ushort4*>(VT + ((size_t)bh * HD_ + d0 + dr) * S_ + s0 + tc4) = o;
  }
}

// ---------------- scores + softmax -> attn (fp32) ----------------
// 16 q-rows per block, 512 threads (8 waves x 128 k-cols). LDS 66 KB -> 2 blocks/CU.
#define SST 1032
__global__ __launch_bounds__(512) void k_attn_sm(const unsigned short* __restrict__ Qcat,
                                                 const unsigned short* __restrict__ Kcat,
                                                 float* __restrict__ attn_out) {
  __shared__ float P[16 * SST];
  const int blk = blockIdx.x;
  const int bh = blk >> 6, q0 = (blk & 63) * 16;
  const int tid = threadIdx.x;
  const int wave = tid >> 6, lane = tid & 63;
  const int l16 = lane & 15, kg = lane >> 4;

  const unsigned short* Qb = Qcat + ((size_t)bh * S_ + q0) * CATD;
  const unsigned short* Kb = Kcat + (size_t)bh * S_ * CATD;
  s16x8 qf[6];
#pragma unroll
  for (int ks = 0; ks < 6; ++ks)
    qf[ks] = *reinterpret_cast<const s16x8*>(Qb + (size_t)l16 * CATD + ks * 32 + kg * 8);

  const int cw = wave * 128;
  f32x4 acc[8] = {};
#pragma unroll
  for (int ni = 0; ni < 8; ++ni) {
    const unsigned short* Kn = Kb + (size_t)(cw + ni * 16 + l16) * CATD + kg * 8;
#pragma unroll
    for (int ks = 0; ks < 6; ++ks)
      acc[ni] = mfma16(qf[ks], *reinterpret_cast<const s16x8*>(Kn + ks * 32), acc[ni]);
  }
  const float scale = 0.07216878364870323f;   // 192^-0.5
#pragma unroll
  for (int ni = 0; ni < 8; ++ni) {
    const int col = cw + ni * 16 + l16;
#pragma unroll
    for (int j = 0; j < 4; ++j)
      P[(kg * 4 + j) * SST + col] = acc[ni][j] * scale;
  }
  __syncthreads();

  // softmax: 32 lanes per row, scores held in registers after one LDS read
  const int r = tid >> 5, li = tid & 31;
  const float* Pr = P + r * SST;
  float4 e[8];
  float m = -1e30f;
#pragma unroll
  for (int ch = 0; ch < 8; ++ch) {
    e[ch] = *reinterpret_cast<const float4*>(Pr + li * 4 + ch * 128);
    m = fmaxf(m, fmaxf(fmaxf(e[ch].x, e[ch].y), fmaxf(e[ch].z, e[ch].w)));
  }
#pragma unroll
  for (int off = 16; off; off >>= 1) m = fmaxf(m, __shfl_xor(m, off, 32));
  float sum = 0.f;
#pragma unroll
  for (int ch = 0; ch < 8; ++ch) {
    e[ch].x = __expf(e[ch].x - m); e[ch].y = __expf(e[ch].y - m);
    e[ch].z = __expf(e[ch].z - m); e[ch].w = __expf(e[ch].w - m);
    sum += (e[ch].x + e[ch].y) + (e[ch].z + e[ch].w);
  }
#pragma unroll
  for (int off = 16; off; off >>= 1) sum += __shfl_xor(sum, off, 32);
  const float rl = 1.0f / sum;
  float* Ao = attn_out + ((size_t)bh * S_ + q0 + r) * S_;
#pragma unroll
  for (int ch = 0; ch < 8; ++ch) {
    float4 w4;
    w4.x = e[ch].x * rl; w4.y = e[ch].y * rl; w4.z = e[ch].z * rl; w4.w = e[ch].w * rl;
    *reinterpret_cast<float4*>(Ao + li * 4 + ch * 128) = w4;
  }
}

// ---------------- PV: batched GEMM ctx[bh] = attn[bh] @ VT[bh]^T, bf16 out ------
__global__ __launch_bounds__(256) void k_pv(const float* __restrict__ attn,
                                            const unsigned short* __restrict__ VT,
                                            unsigned short* __restrict__ ctx) {
  __shared__ unsigned short As[128 * 40];   // padded: reg-staged fp32->bf16 writes
  __shared__ unsigned short Bs[128 * 32];   // linear: global_load_lds
  const int bh = blockIdx.z, b = bh >> 4, h = bh & 15;
  const int tm = blockIdx.x * 128;
  const int tid = threadIdx.x;
  const int wave = tid >> 6, lane = tid & 63;
  const int wr = (wave >> 1) * 64, wc = (wave & 1) * 64;
  const int l16 = lane & 15, kg = lane >> 4;
  const int r0s = tid >> 2, c0s = (tid & 3) * 8;
  const int ra = tid >> 1, ha = (tid & 1) * 16;

  const float* Ag = attn + ((size_t)bh * S_ + tm) * S_;
  const unsigned short* Bg = VT + (size_t)bh * HD_ * S_;
  f32x4 acc[4][4] = {};

  for (int k0 = 0; k0 < S_; k0 += 32) {
    __syncthreads();
    const float* Ap = Ag + (size_t)ra * S_ + k0 + ha;
    const float4 v0 = *reinterpret_cast<const float4*>(Ap);
    const float4 v1 = *reinterpret_cast<const float4*>(Ap + 4);
    const float4 v2 = *reinterpret_cast<const float4*>(Ap + 8);
    const float4 v3 = *reinterpret_cast<const float4*>(Ap + 12);
    *reinterpret_cast<s16x8*>(&As[ra * 40 + ha])     = pk8(v0, v1);
    *reinterpret_cast<s16x8*>(&As[ra * 40 + ha + 8]) = pk8(v2, v3);
    gl_lds16(Bg + (size_t)r0s * S_ + k0 + c0s,        (void*)&Bs[tid * 8]);
    gl_lds16(Bg + (size_t)(r0s + 64) * S_ + k0 + c0s, (void*)&Bs[(tid + 256) * 8]);
    __syncthreads();
    s16x8 af[4], bf4[4];
#pragma unroll
    for (int i = 0; i < 4; ++i)
      af[i] = *reinterpret_cast<const s16x8*>(&As[(wr + i * 16 + l16) * 40 + kg * 8]);
#pragma unroll
    for (int i = 0; i < 4; ++i)
      bf4[i] = *reinterpret_cast<const s16x8*>(&Bs[(wc + i * 16 + l16) * 32 + kg * 8]);
#pragma unroll
    for (int mi = 0; mi < 4; ++mi)
#pragma unroll
      for (int ni = 0; ni < 4; ++ni)
        acc[mi][ni] = mfma16(af[mi], bf4[ni], acc[mi][ni]);
  }

#pragma unroll
  for (int mi = 0; mi < 4; ++mi)
#pragma unroll
    for (int ni = 0; ni < 4; ++ni) {
      const int rr = tm + wr + mi * 16 + kg * 4;
      const int cc = wc + ni * 16 + l16;
#pragma unroll
      for (int j = 0; j < 4; ++j)
        ctx[((size_t)(b * S_ + rr + j)) * DM_ + h * HD_ + cc] = f2b(acc[mi][ni][j]);
    }
}

// ---------------- host launch ----------------
extern "C" void kernel_launch(void* const* d_in, const int* in_sizes, int n_in,
                              void* d_out, int out_size, void* d_ws, size_t ws_size,
                              hipStream_t stream) {
  const float* x         = (const float*)d_in[0];
  const float* Wq_down   = (const float*)d_in[1];
  const float* q_norm_w  = (const float*)d_in[2];
  const float* Wq_up     = (const float*)d_in[3];
  const float* Wq_rope   = (const float*)d_in[4];
  const float* Wkv_down  = (const float*)d_in[5];
  const float* kv_norm_w = (const float*)d_in[6];
  const float* Wk_up     = (const float*)d_in[7];
  const float* Wv_up     = (const float*)d_in[8];
  const float* Wk_rope   = (const float*)d_in[9];
  const float* Wout      = (const float*)d_in[10];

  float* out0 = (float*)d_out;
  float* attn = out0 + (size_t)B_ * S_ * DM_;

  char* ws = (char*)d_ws;
  size_t off = 0;
  auto alloc = [&](size_t bytes) -> void* {
    void* p = ws + off;
    off += (bytes + 255) & ~(size_t)255;
    return p;
  };

  unsigned short* xb     = (unsigned short*)alloc((size_t)NTOK * DM_ * 2);
  unsigned short* WdT    = (unsigned short*)alloc((size_t)(DQL_ + DKVL_) * DM_ * 2);
  unsigned short* WrT    = (unsigned short*)alloc((size_t)DM_ * DM_ * 2);
  unsigned short* WqupT  = (unsigned short*)alloc((size_t)DM_ * DQL_ * 2);
  unsigned short* WkvupT = (unsigned short*)alloc((size_t)(2 * DM_) * DKVL_ * 2);
  unsigned short* WoutT  = (unsigned short*)alloc((size_t)DM_ * DM_ * 2);
  float* cdown           = (float*)alloc((size_t)NTOK * (DQL_ + DKVL_) * 4);
  unsigned short* cqb    = (unsigned short*)alloc((size_t)NTOK * DQL_ * 2);
  unsigned short* ckvb   = (unsigned short*)alloc((size_t)NTOK * DKVL_ * 2);
  float* rope2           = (float*)alloc((size_t)NTOK * DM_ * 4);
  float* X               = (float*)alloc((size_t)NTOK * 2 * DM_ * 4);  // up-proj scratch (reused)
  unsigned short* Qcat   = (unsigned short*)alloc((size_t)B_ * H_ * S_ * CATD * 2);
  unsigned short* Kcat   = (unsigned short*)alloc((size_t)B_ * H_ * S_ * CATD * 2);
  unsigned short* VTb    = (unsigned short*)alloc((size_t)B_ * H_ * HD_ * S_ * 2);
  unsigned short* ctxb   = (unsigned short*)alloc((size_t)NTOK * DM_ * 2);

  if (off > ws_size) return;

  // converts + weight transposes (concat layouts)
  k_f2b<<<(NTOK * DM_ / 4 + 255) / 256, 256, 0, stream>>>(x, xb, NTOK * DM_ / 4);
  k_transpose_b<<<dim3(DM_/64, DQL_/64),   256, 0, stream>>>(Wq_down,  WdT,                   DM_,  DQL_);
  k_transpose_b<<<dim3(DM_/64, DKVL_/64),  256, 0, stream>>>(Wkv_down, WdT + (size_t)DQL_*DM_, DM_, DKVL_);
  k_transpose_b<<<dim3(DM_/64, 1024/64),   256, 0, stream>>>(Wq_rope,  WrT,                   DM_,  1024);
  k_transpose_b<<<dim3(DM_/64, 1024/64),   256, 0, stream>>>(Wk_rope,  WrT + (size_t)1024*DM_, DM_, 1024);
  k_transpose_b<<<dim3(DQL_/64, DM_/64),   256, 0, stream>>>(Wq_up,    WqupT,                 DQL_, DM_);
  k_transpose_b<<<dim3(DKVL_/64, DM_/64),  256, 0, stream>>>(Wk_up,    WkvupT,                DKVL_, DM_);
  k_transpose_b<<<dim3(DKVL_/64, DM_/64),  256, 0, stream>>>(Wv_up,    WkvupT + (size_t)DM_*DKVL_, DKVL_, DM_);
  k_transpose_b<<<dim3(DM_/64, DM_/64),    256, 0, stream>>>(Wout,     WoutT,                 DM_,  DM_);

  // fused down-proj (q|kv), rmsnorms
  k_gemm<<<dim3(NTOK/128, (DQL_+DKVL_)/128), 256, 0, stream>>>(xb, WdT, cdown, NTOK, DQL_+DKVL_, DM_);
  k_rmsnorm<<<NTOK, 64, 0, stream>>>(cdown,        DQL_+DKVL_, q_norm_w,  cqb,  DQL_);
  k_rmsnorm<<<NTOK, 64, 0, stream>>>(cdown + DQL_, DQL_+DKVL_, kv_norm_w, ckvb, DKVL_);

  // fused rope-proj (q|k)
  k_gemm<<<dim3(NTOK/128, DM_/128), 256, 0, stream>>>(xb, WrT, rope2, NTOK, DM_, DM_);

  // Q path
  k_gemm<<<dim3(NTOK/128, DM_/128), 256, 0, stream>>>(cqb, WqupT, X, NTOK, DM_, DQL_);
  k_build_cat<<<NTOK, 256, 0, stream>>>(X, DM_, rope2, DM_, Qcat);

  // K|V path (fused up-proj, N=4096)
  k_gemm<<<dim3(NTOK/128, (2*DM_)/128), 256, 0, stream>>>(ckvb, WkvupT, X, NTOK, 2*DM_, DKVL_);
  k_build_cat<<<NTOK, 256, 0, stream>>>(X, 2*DM_, rope2 + 1024, DM_, Kcat);
  k_pack_vt<<<dim3(B_*H_, S_/64, HD_/64), 256, 0, stream>>>(X + DM_, 2*DM_, VTb);

  // attention
  k_attn_sm<<<B_*H_*(S_/16), 512, 0, stream>>>(Qcat, Kcat, attn);
  k_pv<<<dim3(S_/128, 1, B_*H_), 256, 0, stream>>>(attn, VTb, ctxb);

  // output projection
  k_gemm<<<dim3(NTOK/128, DM_/128), 256, 0, stream>>>(ctxb, WoutT, out0, NTOK, DM_, DM_);
}

// Round 3
// 355.157 us; speedup vs baseline: 1.4519x; 1.1376x over previous
//
#include <hip/hip_runtime.h>

#define B_    2
#define S_    1024
#define DM_   2048
#define H_    16
#define HD_   128
#define RD_   64
#define DQL_  384
#define DKVL_ 512
#define NTOK  (B_*S_)
#define CATD  (HD_+RD_)

typedef float f32x4 __attribute__((ext_vector_type(4)));
typedef short s16x8 __attribute__((ext_vector_type(8)));
typedef unsigned int u32;

__device__ __forceinline__ unsigned short f2b(float f) {   // fp32 -> bf16 RNE
  u32 u = __float_as_uint(f);
  u = (u + 0x7FFFu + ((u >> 16) & 1u)) >> 16;
  return (unsigned short)u;
}
__device__ __forceinline__ f32x4 mfma16(s16x8 a, s16x8 b, f32x4 c) {
  return __builtin_amdgcn_mfma_f32_16x16x32_bf16(a, b, c, 0, 0, 0);
}
__device__ __forceinline__ void gl_lds16(const void* g, void* l) {
  __builtin_amdgcn_global_load_lds((const __attribute__((address_space(1))) u32*)g,
                                   (__attribute__((address_space(3))) u32*)l, 16, 0, 0);
}
__device__ __forceinline__ s16x8 pk8(float4 a, float4 b) {
  s16x8 r;
  r[0]=(short)f2b(a.x); r[1]=(short)f2b(a.y); r[2]=(short)f2b(a.z); r[3]=(short)f2b(a.w);
  r[4]=(short)f2b(b.x); r[5]=(short)f2b(b.y); r[6]=(short)f2b(b.z); r[7]=(short)f2b(b.w);
  return r;
}

// ---------------- fp32 -> bf16 elementwise ----------------
__global__ __launch_bounds__(256) void k_f2b(const float* __restrict__ in,
                                             unsigned short* __restrict__ out, int n4) {
  int i = blockIdx.x * 256 + threadIdx.x;
  if (i >= n4) return;
  const float4 v = reinterpret_cast<const float4*>(in)[i];
  ushort4 o;
  o.x = f2b(v.x); o.y = f2b(v.y); o.z = f2b(v.z); o.w = f2b(v.w);
  reinterpret_cast<ushort4*>(out)[i] = o;
}

// ---------------- fp32 (R x C) -> bf16 transposed (C x R) ----------------
__global__ __launch_bounds__(256) void k_transpose_b(const float* __restrict__ in,
                                                     unsigned short* __restrict__ out,
                                                     int R, int C) {
  __shared__ float tile[64][65];
  const int r0 = blockIdx.x * 64, c0 = blockIdx.y * 64;
  const int t = threadIdx.x;
  const int tr = t >> 4, tc4 = (t & 15) * 4;
#pragma unroll
  for (int i = 0; i < 4; ++i) {
    const int rr = tr + i * 16;
    const float4 v = *reinterpret_cast<const float4*>(in + (size_t)(r0 + rr) * C + c0 + tc4);
    tile[rr][tc4 + 0] = v.x; tile[rr][tc4 + 1] = v.y;
    tile[rr][tc4 + 2] = v.z; tile[rr][tc4 + 3] = v.w;
  }
  __syncthreads();
#pragma unroll
  for (int i = 0; i < 4; ++i) {
    const int oc = tr + i * 16;
    ushort4 o;
    o.x = f2b(tile[tc4 + 0][oc]); o.y = f2b(tile[tc4 + 1][oc]);
    o.z = f2b(tile[tc4 + 2][oc]); o.w = f2b(tile[tc4 + 3][oc]);
    *reinterpret_cast<ushort4*>(out + (size_t)(c0 + oc) * R + r0 + tc4) = o;
  }
}

// ---------------- bf16 GEMM, m97 structure ----------------
__global__ __launch_bounds__(256) void k_gemm(const unsigned short* __restrict__ A,
                                              const unsigned short* __restrict__ Bt,
                                              float* __restrict__ C,
                                              int M, int N, int K) {
  __shared__ unsigned short As[128 * 32];
  __shared__ unsigned short Bs[128 * 32];
  const int nwg = gridDim.x * gridDim.y;
  int id = blockIdx.y * gridDim.x + blockIdx.x;
  id = (id & 7) * (nwg >> 3) + (id >> 3);
  const int tm = (id % gridDim.x) * 128;
  const int tn = (id / gridDim.x) * 128;

  const int tid = threadIdx.x;
  const int wave = tid >> 6, lane = tid & 63;
  const int wr = (wave >> 1) * 64, wc = (wave & 1) * 64;
  const int l16 = lane & 15, kg = lane >> 4;
  const int r0s = tid >> 2, c0s = (tid & 3) * 8;

  const unsigned short* Ag = A + (size_t)tm * K;
  const unsigned short* Bg = Bt + (size_t)tn * K;
  f32x4 acc[4][4] = {};

  for (int k0 = 0; k0 < K; k0 += 32) {
    __syncthreads();
    gl_lds16(Ag + (size_t)r0s * K + k0 + c0s,        (void*)&As[tid * 8]);
    gl_lds16(Ag + (size_t)(r0s + 64) * K + k0 + c0s, (void*)&As[(tid + 256) * 8]);
    gl_lds16(Bg + (size_t)r0s * K + k0 + c0s,        (void*)&Bs[tid * 8]);
    gl_lds16(Bg + (size_t)(r0s + 64) * K + k0 + c0s, (void*)&Bs[(tid + 256) * 8]);
    __syncthreads();
    s16x8 af[4], bf4[4];
#pragma unroll
    for (int i = 0; i < 4; ++i)
      af[i] = *reinterpret_cast<const s16x8*>(&As[(wr + i * 16 + l16) * 32 + kg * 8]);
#pragma unroll
    for (int i = 0; i < 4; ++i)
      bf4[i] = *reinterpret_cast<const s16x8*>(&Bs[(wc + i * 16 + l16) * 32 + kg * 8]);
#pragma unroll
    for (int mi = 0; mi < 4; ++mi)
#pragma unroll
      for (int ni = 0; ni < 4; ++ni)
        acc[mi][ni] = mfma16(af[mi], bf4[ni], acc[mi][ni]);
  }

#pragma unroll
  for (int mi = 0; mi < 4; ++mi)
#pragma unroll
    for (int ni = 0; ni < 4; ++ni) {
      const int rr = tm + wr + mi * 16 + kg * 4;
      const int cc = tn + wc + ni * 16 + l16;
#pragma unroll
      for (int j = 0; j < 4; ++j)
        C[(size_t)(rr + j) * N + cc] = acc[mi][ni][j];
    }
}

// ---------------- RMSNorm (strided input) ----------------
__global__ __launch_bounds__(64) void k_rmsnorm(const float* __restrict__ in, int stride,
                                                const float* __restrict__ w,
                                                unsigned short* __restrict__ out, int D) {
  const int row = blockIdx.x;
  const float* x = in + (size_t)row * stride;
  float ss = 0.f;
  for (int i = threadIdx.x; i < D; i += 64) { const float v = x[i]; ss = fmaf(v, v, ss); }
#pragma unroll
  for (int off = 32; off; off >>= 1) ss += __shfl_xor(ss, off, 64);
  const float r = rsqrtf(ss / (float)D + 1e-6f);
  for (int i = threadIdx.x; i < D; i += 64)
    out[(size_t)row * D + i] = f2b(x[i] * r * w[i]);
}

// ---------------- build concat(up | rope) -> [B*H][S][192] bf16 (scale folded) --
__global__ __launch_bounds__(256) void k_build_cat(const float* __restrict__ up, int ustride,
                                                   const float* __restrict__ rope, int rstride,
                                                   unsigned short* __restrict__ cat,
                                                   float qsc) {
  const int bs = blockIdx.x;
  const int b = bs >> 10, s = bs & 1023;
  const int t = threadIdx.x;
  for (int e = t; e < 2048; e += 256) {
    const int h = e >> 7, d = e & 127;
    cat[((size_t)(b * H_ + h) * S_ + s) * CATD + d] = f2b(up[(size_t)bs * ustride + e] * qsc);
  }
  for (int pp = t; pp < 512; pp += 256) {
    const int h = pp >> 5, p = pp & 31;
    const float xe = rope[(size_t)bs * rstride + h * 64 + 2 * p];
    const float xo = rope[(size_t)bs * rstride + h * 64 + 2 * p + 1];
    const float freq = powf(10000.0f, -(float)(2 * p) / 64.0f);
    const float ang = (float)s * freq;
    float sn, cs;
    sincosf(ang, &sn, &cs);
    unsigned short* o = &cat[((size_t)(b * H_ + h) * S_ + s) * CATD + HD_ + 2 * p];
    o[0] = f2b((xe * cs - xo * sn) * qsc);
    o[1] = f2b((xe * sn + xo * cs) * qsc);
  }
}

// ---------------- pack V transposed: [B*H][HD][S] bf16 ----------------
__global__ __launch_bounds__(256) void k_pack_vt(const float* __restrict__ v, int vstride,
                                                 unsigned short* __restrict__ VT) {
  __shared__ float tile[64][65];
  const int bh = blockIdx.x;
  const int s0 = blockIdx.y * 64, d0 = blockIdx.z * 64;
  const int b = bh >> 4, h = bh & 15;
  const int t = threadIdx.x;
  const int tr = t >> 4, tc4 = (t & 15) * 4;
#pragma unroll
  for (int i = 0; i < 4; ++i) {
    const int sr = tr + i * 16;
    const float4 vv = *reinterpret_cast<const float4*>(
        v + (size_t)(b * S_ + s0 + sr) * vstride + h * HD_ + d0 + tc4);
    tile[sr][tc4 + 0] = vv.x; tile[sr][tc4 + 1] = vv.y;
    tile[sr][tc4 + 2] = vv.z; tile[sr][tc4 + 3] = vv.w;
  }
  __syncthreads();
#pragma unroll
  for (int i = 0; i < 4; ++i) {
    const int dr = tr + i * 16;
    ushort4 o;
    o.x = f2b(tile[tc4 + 0][dr]); o.y = f2b(tile[tc4 + 1][dr]);
    o.z = f2b(tile[tc4 + 2][dr]); o.w = f2b(tile[tc4 + 3][dr]);
    *reinterpret_cast<ushort4*>(VT + ((size_t)bh * HD_ + d0 + dr) * S_ + s0 + tc4) = o;
  }
}

// ---------------- attention scores+softmax, two-pass, register scores ----------
// 256 blocks = 32 bh x 8 q-chunks(128). 512 thr = 8 waves x 16 q-rows.
// K chunk (128x192 bf16, 48KB) staged in LDS with XOR-swizzled granules via
// pre-swizzled global source (global_load_lds dest must be linear).
#define KVB 128
__global__ __launch_bounds__(512, 2) void k_attn2(const unsigned short* __restrict__ Qcat,
                                                  const unsigned short* __restrict__ Kcat,
                                                  float* __restrict__ attn_out) {
  __shared__ unsigned short Ks[KVB * 192];   // 48 KB
  // XCD-bijective remap: each XCD owns 4 whole bh (K stays in its L2)
  const int d = blockIdx.x;
  const int xcd = d & 7, i = d >> 3;
  const int bh = xcd | ((i >> 3) << 3);
  const int qc = i & 7;

  const int tid = threadIdx.x, wave = tid >> 6, lane = tid & 63;
  const int l16 = lane & 15, kg = lane >> 4;
  const int qw = qc * 128 + wave * 16;

  // Q fragments (B operand): lane: q = qw + l16, d-slice = ks*32 + kg*8
  const unsigned short* Qb = Qcat + ((size_t)bh * S_ + qw) * CATD;
  s16x8 qf[6];
#pragma unroll
  for (int ks = 0; ks < 6; ++ks)
    qf[ks] = *reinterpret_cast<const s16x8*>(Qb + (size_t)l16 * CATD + ks * 32 + kg * 8);

  // staging map: slot s = j*512+tid -> row=s/24, fetch granule (s%24)^(row&7)
  int srow[6], scol[6];
#pragma unroll
  for (int j = 0; j < 6; ++j) {
    const int s = j * 512 + tid;
    srow[j] = s / 24;
    scol[j] = ((s % 24) ^ (srow[j] & 7)) * 8;
  }
  const unsigned short* Kb = Kcat + (size_t)bh * S_ * CATD;

  float mx = -1e30f, sm = 0.f, rl = 0.f;

  for (int pass = 0; pass < 2; ++pass) {
    for (int ch = 0; ch < S_ / KVB; ++ch) {
      __syncthreads();                      // all waves done with previous chunk
      const unsigned short* Kc = Kb + (size_t)ch * KVB * CATD;
#pragma unroll
      for (int j = 0; j < 6; ++j)
        gl_lds16(Kc + (size_t)srow[j] * CATD + scol[j], (void*)&Ks[(j * 512 + tid) * 8]);
      __syncthreads();                      // implicit vmcnt(0) drain -> data ready

      f32x4 acc[8] = {};
#pragma unroll
      for (int ni = 0; ni < 8; ++ni) {
        const int row = ni * 16 + l16;
#pragma unroll
        for (int ks = 0; ks < 6; ++ks) {
          const int slot = (ks * 4 + kg) ^ (l16 & 7);
          const s16x8 af = *reinterpret_cast<const s16x8*>(&Ks[row * 192 + slot * 8]);
          acc[ni] = mfma16(af, qf[ks], acc[ni]);
        }
      }

      if (pass == 0) {
        float cm = -1e30f;
#pragma unroll
        for (int ni = 0; ni < 8; ++ni)
#pragma unroll
          for (int j = 0; j < 4; ++j) cm = fmaxf(cm, acc[ni][j]);
        const float nm = fmaxf(mx, cm);
        sm *= __expf(mx - nm);
#pragma unroll
        for (int ni = 0; ni < 8; ++ni)
#pragma unroll
          for (int j = 0; j < 4; ++j) sm += __expf(acc[ni][j] - nm);
        mx = nm;
      } else {
        float* Ao = attn_out + ((size_t)bh * S_ + qw + l16) * S_ + ch * KVB;
#pragma unroll
        for (int ni = 0; ni < 8; ++ni) {
          float4 w4;
          w4.x = __expf(acc[ni][0] - mx) * rl;
          w4.y = __expf(acc[ni][1] - mx) * rl;
          w4.z = __expf(acc[ni][2] - mx) * rl;
          w4.w = __expf(acc[ni][3] - mx) * rl;
          *reinterpret_cast<float4*>(Ao + ni * 16 + kg * 4) = w4;
        }
      }
    }
    if (pass == 0) {
      // combine the 4 disjoint k-subsets held by lane groups {l16, +16, +32, +48}
#pragma unroll
      for (int off = 16; off < 64; off <<= 1) {
        const float om = __shfl_xor(mx, off, 64);
        const float os = __shfl_xor(sm, off, 64);
        const float nm = fmaxf(mx, om);
        sm = sm * __expf(mx - nm) + os * __expf(om - nm);
        mx = nm;
      }
      rl = 1.0f / sm;
    }
  }
}

// ---------------- PV: batched GEMM ctx[bh] = attn[bh] @ VT[bh]^T, bf16 out ------
__global__ __launch_bounds__(256) void k_pv(const float* __restrict__ attn,
                                            const unsigned short* __restrict__ VT,
                                            unsigned short* __restrict__ ctx) {
  __shared__ unsigned short As[128 * 40];
  __shared__ unsigned short Bs[128 * 32];
  const int bh = blockIdx.z, b = bh >> 4, h = bh & 15;
  const int tm = blockIdx.x * 128;
  const int tid = threadIdx.x;
  const int wave = tid >> 6, lane = tid & 63;
  const int wr = (wave >> 1) * 64, wc = (wave & 1) * 64;
  const int l16 = lane & 15, kg = lane >> 4;
  const int r0s = tid >> 2, c0s = (tid & 3) * 8;
  const int ra = tid >> 1, ha = (tid & 1) * 16;

  const float* Ag = attn + ((size_t)bh * S_ + tm) * S_;
  const unsigned short* Bg = VT + (size_t)bh * HD_ * S_;
  f32x4 acc[4][4] = {};

  for (int k0 = 0; k0 < S_; k0 += 32) {
    __syncthreads();
    const float* Ap = Ag + (size_t)ra * S_ + k0 + ha;
    const float4 v0 = *reinterpret_cast<const float4*>(Ap);
    const float4 v1 = *reinterpret_cast<const float4*>(Ap + 4);
    const float4 v2 = *reinterpret_cast<const float4*>(Ap + 8);
    const float4 v3 = *reinterpret_cast<const float4*>(Ap + 12);
    *reinterpret_cast<s16x8*>(&As[ra * 40 + ha])     = pk8(v0, v1);
    *reinterpret_cast<s16x8*>(&As[ra * 40 + ha + 8]) = pk8(v2, v3);
    gl_lds16(Bg + (size_t)r0s * S_ + k0 + c0s,        (void*)&Bs[tid * 8]);
    gl_lds16(Bg + (size_t)(r0s + 64) * S_ + k0 + c0s, (void*)&Bs[(tid + 256) * 8]);
    __syncthreads();
    s16x8 af[4], bf4[4];
#pragma unroll
    for (int i = 0; i < 4; ++i)
      af[i] = *reinterpret_cast<const s16x8*>(&As[(wr + i * 16 + l16) * 40 + kg * 8]);
#pragma unroll
    for (int i = 0; i < 4; ++i)
      bf4[i] = *reinterpret_cast<const s16x8*>(&Bs[(wc + i * 16 + l16) * 32 + kg * 8]);
#pragma unroll
    for (int mi = 0; mi < 4; ++mi)
#pragma unroll
      for (int ni = 0; ni < 4; ++ni)
        acc[mi][ni] = mfma16(af[mi], bf4[ni], acc[mi][ni]);
  }

#pragma unroll
  for (int mi = 0; mi < 4; ++mi)
#pragma unroll
    for (int ni = 0; ni < 4; ++ni) {
      const int rr = tm + wr + mi * 16 + kg * 4;
      const int cc = wc + ni * 16 + l16;
#pragma unroll
      for (int j = 0; j < 4; ++j)
        ctx[((size_t)(b * S_ + rr + j)) * DM_ + h * HD_ + cc] = f2b(acc[mi][ni][j]);
    }
}

// ---------------- host launch ----------------
extern "C" void kernel_launch(void* const* d_in, const int* in_sizes, int n_in,
                              void* d_out, int out_size, void* d_ws, size_t ws_size,
                              hipStream_t stream) {
  const float* x         = (const float*)d_in[0];
  const float* Wq_down   = (const float*)d_in[1];
  const float* q_norm_w  = (const float*)d_in[2];
  const float* Wq_up     = (const float*)d_in[3];
  const float* Wq_rope   = (const float*)d_in[4];
  const float* Wkv_down  = (const float*)d_in[5];
  const float* kv_norm_w = (const float*)d_in[6];
  const float* Wk_up     = (const float*)d_in[7];
  const float* Wv_up     = (const float*)d_in[8];
  const float* Wk_rope   = (const float*)d_in[9];
  const float* Wout      = (const float*)d_in[10];

  float* out0 = (float*)d_out;
  float* attn = out0 + (size_t)B_ * S_ * DM_;

  char* ws = (char*)d_ws;
  size_t off = 0;
  auto alloc = [&](size_t bytes) -> void* {
    void* p = ws + off;
    off += (bytes + 255) & ~(size_t)255;
    return p;
  };

  unsigned short* xb     = (unsigned short*)alloc((size_t)NTOK * DM_ * 2);
  unsigned short* WdT    = (unsigned short*)alloc((size_t)(DQL_ + DKVL_) * DM_ * 2);
  unsigned short* WrT    = (unsigned short*)alloc((size_t)DM_ * DM_ * 2);
  unsigned short* WqupT  = (unsigned short*)alloc((size_t)DM_ * DQL_ * 2);
  unsigned short* WkvupT = (unsigned short*)alloc((size_t)(2 * DM_) * DKVL_ * 2);
  unsigned short* WoutT  = (unsigned short*)alloc((size_t)DM_ * DM_ * 2);
  float* cdown           = (float*)alloc((size_t)NTOK * (DQL_ + DKVL_) * 4);
  unsigned short* cqb    = (unsigned short*)alloc((size_t)NTOK * DQL_ * 2);
  unsigned short* ckvb   = (unsigned short*)alloc((size_t)NTOK * DKVL_ * 2);
  float* rope2           = (float*)alloc((size_t)NTOK * DM_ * 4);
  float* X               = (float*)alloc((size_t)NTOK * 2 * DM_ * 4);
  unsigned short* Qcat   = (unsigned short*)alloc((size_t)B_ * H_ * S_ * CATD * 2);
  unsigned short* Kcat   = (unsigned short*)alloc((size_t)B_ * H_ * S_ * CATD * 2);
  unsigned short* VTb    = (unsigned short*)alloc((size_t)B_ * H_ * HD_ * S_ * 2);
  unsigned short* ctxb   = (unsigned short*)alloc((size_t)NTOK * DM_ * 2);

  if (off > ws_size) return;

  k_f2b<<<(NTOK * DM_ / 4 + 255) / 256, 256, 0, stream>>>(x, xb, NTOK * DM_ / 4);
  k_transpose_b<<<dim3(DM_/64, DQL_/64),   256, 0, stream>>>(Wq_down,  WdT,                   DM_,  DQL_);
  k_transpose_b<<<dim3(DM_/64, DKVL_/64),  256, 0, stream>>>(Wkv_down, WdT + (size_t)DQL_*DM_, DM_, DKVL_);
  k_transpose_b<<<dim3(DM_/64, 1024/64),   256, 0, stream>>>(Wq_rope,  WrT,                   DM_,  1024);
  k_transpose_b<<<dim3(DM_/64, 1024/64),   256, 0, stream>>>(Wk_rope,  WrT + (size_t)1024*DM_, DM_, 1024);
  k_transpose_b<<<dim3(DQL_/64, DM_/64),   256, 0, stream>>>(Wq_up,    WqupT,                 DQL_, DM_);
  k_transpose_b<<<dim3(DKVL_/64, DM_/64),  256, 0, stream>>>(Wk_up,    WkvupT,                DKVL_, DM_);
  k_transpose_b<<<dim3(DKVL_/64, DM_/64),  256, 0, stream>>>(Wv_up,    WkvupT + (size_t)DM_*DKVL_, DKVL_, DM_);
  k_transpose_b<<<dim3(DM_/64, DM_/64),    256, 0, stream>>>(Wout,     WoutT,                 DM_,  DM_);

  k_gemm<<<dim3(NTOK/128, (DQL_+DKVL_)/128), 256, 0, stream>>>(xb, WdT, cdown, NTOK, DQL_+DKVL_, DM_);
  k_rmsnorm<<<NTOK, 64, 0, stream>>>(cdown,        DQL_+DKVL_, q_norm_w,  cqb,  DQL_);
  k_rmsnorm<<<NTOK, 64, 0, stream>>>(cdown + DQL_, DQL_+DKVL_, kv_norm_w, ckvb, DKVL_);

  k_gemm<<<dim3(NTOK/128, DM_/128), 256, 0, stream>>>(xb, WrT, rope2, NTOK, DM_, DM_);

  const float qsc = 0.07216878364870323f;   // 192^-0.5 folded into Q
  k_gemm<<<dim3(NTOK/128, DM_/128), 256, 0, stream>>>(cqb, WqupT, X, NTOK, DM_, DQL_);
  k_build_cat<<<NTOK, 256, 0, stream>>>(X, DM_, rope2, DM_, Qcat, qsc);

  k_gemm<<<dim3(NTOK/128, (2*DM_)/128), 256, 0, stream>>>(ckvb, WkvupT, X, NTOK, 2*DM_, DKVL_);
  k_build_cat<<<NTOK, 256, 0, stream>>>(X, 2*DM_, rope2 + 1024, DM_, Kcat, 1.0f);
  k_pack_vt<<<dim3(B_*H_, S_/64, HD_/64), 256, 0, stream>>>(X + DM_, 2*DM_, VTb);

  k_attn2<<<256, 512, 0, stream>>>(Qcat, Kcat, attn);
  k_pv<<<dim3(S_/128, 1, B_*H_), 256, 0, stream>>>(attn, VTb, ctxb);

  k_gemm<<<dim3(NTOK/128, DM_/128), 256, 0, stream>>>(ctxb, WoutT, out0, NTOK, DM_, DM_);
}

// Round 4
// 271.953 us; speedup vs baseline: 1.8960x; 1.3059x over previous
//
#include <hip/hip_runtime.h>

#define B_    2
#define S_    1024
#define DM_   2048
#define H_    16
#define HD_   128
#define RD_   64
#define DQL_  384
#define DKVL_ 512
#define NTOK  (B_*S_)
#define CATD  (HD_+RD_)

typedef float f32x4 __attribute__((ext_vector_type(4)));
typedef short s16x8 __attribute__((ext_vector_type(8)));
typedef unsigned int u32;

__device__ __forceinline__ unsigned short f2b(float f) {   // fp32 -> bf16 RNE
  u32 u = __float_as_uint(f);
  u = (u + 0x7FFFu + ((u >> 16) & 1u)) >> 16;
  return (unsigned short)u;
}
__device__ __forceinline__ f32x4 mfma16(s16x8 a, s16x8 b, f32x4 c) {
  return __builtin_amdgcn_mfma_f32_16x16x32_bf16(a, b, c, 0, 0, 0);
}
__device__ __forceinline__ void gl_lds16(const void* g, void* l) {
  __builtin_amdgcn_global_load_lds((const __attribute__((address_space(1))) u32*)g,
                                   (__attribute__((address_space(3))) u32*)l, 16, 0, 0);
}
__device__ __forceinline__ s16x8 pk8(float4 a, float4 b) {
  s16x8 r;
  r[0]=(short)f2b(a.x); r[1]=(short)f2b(a.y); r[2]=(short)f2b(a.z); r[3]=(short)f2b(a.w);
  r[4]=(short)f2b(b.x); r[5]=(short)f2b(b.y); r[6]=(short)f2b(b.z); r[7]=(short)f2b(b.w);
  return r;
}

// ---------------- rope cos/sin table: csT[s][p] = {cos, sin}(s * 10000^(-p/32)) --
__global__ __launch_bounds__(256) void k_rope_tab(float2* __restrict__ csT) {
  const int i = blockIdx.x * 256 + threadIdx.x;       // 32768 = 1024 x 32
  const int s = i >> 5, p = i & 31;
  const float freq = powf(10000.0f, -(float)p / 32.0f);
  float sn, cs;
  sincosf((float)s * freq, &sn, &cs);
  csT[i] = make_float2(cs, sn);
}

// ---------------- fp32 -> bf16 elementwise ----------------
__global__ __launch_bounds__(256) void k_f2b(const float* __restrict__ in,
                                             unsigned short* __restrict__ out, int n4) {
  int i = blockIdx.x * 256 + threadIdx.x;
  if (i >= n4) return;
  const float4 v = reinterpret_cast<const float4*>(in)[i];
  ushort4 o;
  o.x = f2b(v.x); o.y = f2b(v.y); o.z = f2b(v.z); o.w = f2b(v.w);
  reinterpret_cast<ushort4*>(out)[i] = o;
}

// ---------------- fused transpose-convert of all weights ----------------
struct TD { const float* in; unsigned short* out; int R, C, blk0; float scale; };
struct TD8 { TD d[8]; };
__global__ __launch_bounds__(256) void k_transpose_all(TD8 descs) {
  __shared__ float tile[64][65];
  const int bid = blockIdx.x;
  int di = 0;
#pragma unroll
  for (int i = 1; i < 8; ++i) if (bid >= descs.d[i].blk0) di = i;
  const TD dd = descs.d[di];
  const int local = bid - dd.blk0;
  const int tiles_r = dd.R >> 6;
  const int tr_ = local % tiles_r, tc_ = local / tiles_r;
  const int r0 = tr_ * 64, c0 = tc_ * 64;
  const int t = threadIdx.x;
  const int tr = t >> 4, tc4 = (t & 15) * 4;
#pragma unroll
  for (int i = 0; i < 4; ++i) {
    const int rr = tr + i * 16;
    const float4 v = *reinterpret_cast<const float4*>(dd.in + (size_t)(r0 + rr) * dd.C + c0 + tc4);
    tile[rr][tc4 + 0] = v.x; tile[rr][tc4 + 1] = v.y;
    tile[rr][tc4 + 2] = v.z; tile[rr][tc4 + 3] = v.w;
  }
  __syncthreads();
#pragma unroll
  for (int i = 0; i < 4; ++i) {
    const int oc = tr + i * 16;
    ushort4 o;
    o.x = f2b(tile[tc4 + 0][oc] * dd.scale); o.y = f2b(tile[tc4 + 1][oc] * dd.scale);
    o.z = f2b(tile[tc4 + 2][oc] * dd.scale); o.w = f2b(tile[tc4 + 3][oc] * dd.scale);
    *reinterpret_cast<ushort4*>(dd.out + (size_t)(c0 + oc) * dd.R + r0 + tc4) = o;
  }
}

// ---------------- generic m97-structure GEMM (used for Wout) ----------------
__global__ __launch_bounds__(256) void k_gemm(const unsigned short* __restrict__ A,
                                              const unsigned short* __restrict__ Bt,
                                              float* __restrict__ C,
                                              int M, int N, int K) {
  __shared__ unsigned short As[128 * 32];
  __shared__ unsigned short Bs[128 * 32];
  const int nwg = gridDim.x * gridDim.y;
  int id = blockIdx.y * gridDim.x + blockIdx.x;
  id = (id & 7) * (nwg >> 3) + (id >> 3);
  const int tm = (id % gridDim.x) * 128;
  const int tn = (id / gridDim.x) * 128;
  const int tid = threadIdx.x;
  const int wave = tid >> 6, lane = tid & 63;
  const int wr = (wave >> 1) * 64, wc = (wave & 1) * 64;
  const int l16 = lane & 15, kg = lane >> 4;
  const int r0s = tid >> 2, c0s = (tid & 3) * 8;

  const unsigned short* Ag = A + (size_t)tm * K;
  const unsigned short* Bg = Bt + (size_t)tn * K;
  f32x4 acc[4][4] = {};

  for (int k0 = 0; k0 < K; k0 += 32) {
    __syncthreads();
    gl_lds16(Ag + (size_t)r0s * K + k0 + c0s,        (void*)&As[tid * 8]);
    gl_lds16(Ag + (size_t)(r0s + 64) * K + k0 + c0s, (void*)&As[(tid + 256) * 8]);
    gl_lds16(Bg + (size_t)r0s * K + k0 + c0s,        (void*)&Bs[tid * 8]);
    gl_lds16(Bg + (size_t)(r0s + 64) * K + k0 + c0s, (void*)&Bs[(tid + 256) * 8]);
    __syncthreads();
    s16x8 af[4], bf4[4];
#pragma unroll
    for (int i = 0; i < 4; ++i)
      af[i] = *reinterpret_cast<const s16x8*>(&As[(wr + i * 16 + l16) * 32 + kg * 8]);
#pragma unroll
    for (int i = 0; i < 4; ++i)
      bf4[i] = *reinterpret_cast<const s16x8*>(&Bs[(wc + i * 16 + l16) * 32 + kg * 8]);
#pragma unroll
    for (int mi = 0; mi < 4; ++mi)
#pragma unroll
      for (int ni = 0; ni < 4; ++ni)
        acc[mi][ni] = mfma16(af[mi], bf4[ni], acc[mi][ni]);
  }

#pragma unroll
  for (int mi = 0; mi < 4; ++mi)
#pragma unroll
    for (int ni = 0; ni < 4; ++ni) {
      const int rr = tm + wr + mi * 16 + kg * 4;
      const int cc = tn + wc + ni * 16 + l16;
#pragma unroll
      for (int j = 0; j < 4; ++j)
        C[(size_t)(rr + j) * N + cc] = acc[mi][ni][j];
    }
}

// ---------------- launch 1: A=xb. down(N=896)->cdown ; rope(N=2048)->Qcat/Kcat --
__global__ __launch_bounds__(256) void k_proj_a(const unsigned short* __restrict__ xb,
                                                const unsigned short* __restrict__ WdT,
                                                const unsigned short* __restrict__ WrT,
                                                float* __restrict__ cdown,
                                                unsigned short* __restrict__ Qcat,
                                                unsigned short* __restrict__ Kcat,
                                                const float2* __restrict__ csT) {
  __shared__ unsigned short As[128 * 32];
  __shared__ unsigned short Bs[128 * 32];
  int id = blockIdx.x;                       // 368 blocks
  id = (id & 7) * 46 + (id >> 3);            // bijective XCD chunking
  const bool down = id < 112;
  int gm, tn; const unsigned short* Bt;
  if (down) { gm = id % 16; tn = (id / 16) * 128; Bt = WdT; }
  else { const int i2 = id - 112; gm = i2 % 16; tn = (i2 / 16) * 128; Bt = WrT; }
  const int tm = gm * 128;

  const int tid = threadIdx.x;
  const int wave = tid >> 6, lane = tid & 63;
  const int wr = (wave >> 1) * 64, wc = (wave & 1) * 64;
  const int l16 = lane & 15, kg = lane >> 4;
  const int r0s = tid >> 2, c0s = (tid & 3) * 8;

  const unsigned short* Ag = xb + (size_t)tm * DM_;
  const unsigned short* Bg = Bt + (size_t)tn * DM_;
  f32x4 acc[4][4] = {};

  for (int k0 = 0; k0 < DM_; k0 += 32) {
    __syncthreads();
    gl_lds16(Ag + (size_t)r0s * DM_ + k0 + c0s,        (void*)&As[tid * 8]);
    gl_lds16(Ag + (size_t)(r0s + 64) * DM_ + k0 + c0s, (void*)&As[(tid + 256) * 8]);
    gl_lds16(Bg + (size_t)r0s * DM_ + k0 + c0s,        (void*)&Bs[tid * 8]);
    gl_lds16(Bg + (size_t)(r0s + 64) * DM_ + k0 + c0s, (void*)&Bs[(tid + 256) * 8]);
    __syncthreads();
    s16x8 af[4], bf4[4];
#pragma unroll
    for (int i = 0; i < 4; ++i)
      af[i] = *reinterpret_cast<const s16x8*>(&As[(wr + i * 16 + l16) * 32 + kg * 8]);
#pragma unroll
    for (int i = 0; i < 4; ++i)
      bf4[i] = *reinterpret_cast<const s16x8*>(&Bs[(wc + i * 16 + l16) * 32 + kg * 8]);
#pragma unroll
    for (int mi = 0; mi < 4; ++mi)
#pragma unroll
      for (int ni = 0; ni < 4; ++ni)
        acc[mi][ni] = mfma16(af[mi], bf4[ni], acc[mi][ni]);
  }

  if (down) {
#pragma unroll
    for (int mi = 0; mi < 4; ++mi)
#pragma unroll
      for (int ni = 0; ni < 4; ++ni) {
        const int rr = tm + wr + mi * 16 + kg * 4;
        const int cc = tn + wc + ni * 16 + l16;
#pragma unroll
        for (int j = 0; j < 4; ++j)
          cdown[(size_t)(rr + j) * (DQL_ + DKVL_) + cc] = acc[mi][ni][j];
      }
  } else {
    // rope epilogue: pair mix via lane-parity shuffle + cos/sin table
#pragma unroll
    for (int mi = 0; mi < 4; ++mi)
#pragma unroll
      for (int ni = 0; ni < 4; ++ni) {
        const int col = tn + wc + ni * 16 + l16;          // 0..2047 (block-uniform Q/K)
        unsigned short* dst = (col < 1024) ? Qcat : Kcat;
        const int c1 = col & 1023;
        const int hh = c1 >> 6, dd2 = c1 & 63, p = dd2 >> 1, odd = dd2 & 1;
        const int row0 = tm + wr + mi * 16 + kg * 4;
#pragma unroll
        for (int j = 0; j < 4; ++j) {
          const float own = acc[mi][ni][j];
          const float prt = __shfl_xor(own, 1, 64);
          const int tok = row0 + j, b = tok >> 10, s = tok & 1023;
          const float2 cs = csT[s * 32 + p];
          const float o = odd ? (prt * cs.y + own * cs.x) : (own * cs.x - prt * cs.y);
          dst[((size_t)(b * H_ + hh) * S_ + s) * CATD + HD_ + dd2] = f2b(o);
        }
      }
  }
}

// ---------------- launch 2: q-up (A=cqb,K=384,N=2048) + kv-up (A=ckvb,K=512,N=4096)
__global__ __launch_bounds__(256) void k_proj_b(const unsigned short* __restrict__ cqb,
                                                const unsigned short* __restrict__ ckvb,
                                                const unsigned short* __restrict__ WqupT,
                                                const unsigned short* __restrict__ WkvupT,
                                                unsigned short* __restrict__ Qcat,
                                                unsigned short* __restrict__ Kcat,
                                                unsigned short* __restrict__ VTb) {
  __shared__ unsigned short As[128 * 32];
  __shared__ unsigned short Bs[128 * 32];
  int id = blockIdx.x;                       // 768 blocks
  id = (id & 7) * 96 + (id >> 3);
  const bool qgrp = id < 256;
  int gm, tn, K; const unsigned short* Bt; const unsigned short* A;
  if (qgrp) { gm = id & 15; tn = (id >> 4) * 128; Bt = WqupT; A = cqb; K = DQL_; }
  else { const int i2 = id - 256; gm = i2 & 15; tn = (i2 >> 4) * 128; Bt = WkvupT; A = ckvb; K = DKVL_; }
  const int tm = gm * 128;

  const int tid = threadIdx.x;
  const int wave = tid >> 6, lane = tid & 63;
  const int wr = (wave >> 1) * 64, wc = (wave & 1) * 64;
  const int l16 = lane & 15, kg = lane >> 4;
  const int r0s = tid >> 2, c0s = (tid & 3) * 8;

  const unsigned short* Ag = A + (size_t)tm * K;
  const unsigned short* Bg = Bt + (size_t)tn * K;
  f32x4 acc[4][4] = {};

  for (int k0 = 0; k0 < K; k0 += 32) {
    __syncthreads();
    gl_lds16(Ag + (size_t)r0s * K + k0 + c0s,        (void*)&As[tid * 8]);
    gl_lds16(Ag + (size_t)(r0s + 64) * K + k0 + c0s, (void*)&As[(tid + 256) * 8]);
    gl_lds16(Bg + (size_t)r0s * K + k0 + c0s,        (void*)&Bs[tid * 8]);
    gl_lds16(Bg + (size_t)(r0s + 64) * K + k0 + c0s, (void*)&Bs[(tid + 256) * 8]);
    __syncthreads();
    s16x8 af[4], bf4[4];
#pragma unroll
    for (int i = 0; i < 4; ++i)
      af[i] = *reinterpret_cast<const s16x8*>(&As[(wr + i * 16 + l16) * 32 + kg * 8]);
#pragma unroll
    for (int i = 0; i < 4; ++i)
      bf4[i] = *reinterpret_cast<const s16x8*>(&Bs[(wc + i * 16 + l16) * 32 + kg * 8]);
#pragma unroll
    for (int mi = 0; mi < 4; ++mi)
#pragma unroll
      for (int ni = 0; ni < 4; ++ni)
        acc[mi][ni] = mfma16(af[mi], bf4[ni], acc[mi][ni]);
  }

#pragma unroll
  for (int mi = 0; mi < 4; ++mi)
#pragma unroll
    for (int ni = 0; ni < 4; ++ni) {
      const int col = tn + wc + ni * 16 + l16;
      const int row0 = tm + wr + mi * 16 + kg * 4;
      if (qgrp || col < 2048) {
        unsigned short* dst = qgrp ? Qcat : Kcat;
        const int hh = (col & 2047) >> 7, d = col & 127;
#pragma unroll
        for (int j = 0; j < 4; ++j) {
          const int tok = row0 + j, b = tok >> 10, s = tok & 1023;
          dst[((size_t)(b * H_ + hh) * S_ + s) * CATD + d] = f2b(acc[mi][ni][j]);
        }
      } else {
        const int m2 = col - 2048;
        const int hh = m2 >> 7, d = m2 & 127;
        const int b = row0 >> 10, s0 = row0 & 1023;
        ushort4 o;
        o.x = f2b(acc[mi][ni][0]); o.y = f2b(acc[mi][ni][1]);
        o.z = f2b(acc[mi][ni][2]); o.w = f2b(acc[mi][ni][3]);
        *reinterpret_cast<ushort4*>(&VTb[((size_t)(b * H_ + hh) * HD_ + d) * S_ + s0]) = o;
      }
    }
}

// ---------------- RMSNorm (strided input) ----------------
__global__ __launch_bounds__(64) void k_rmsnorm(const float* __restrict__ in, int stride,
                                                const float* __restrict__ w,
                                                unsigned short* __restrict__ out, int D) {
  const int row = blockIdx.x;
  const float* x = in + (size_t)row * stride;
  float ss = 0.f;
  for (int i = threadIdx.x; i < D; i += 64) { const float v = x[i]; ss = fmaf(v, v, ss); }
#pragma unroll
  for (int off = 32; off; off >>= 1) ss += __shfl_xor(ss, off, 64);
  const float r = rsqrtf(ss / (float)D + 1e-6f);
  for (int i = threadIdx.x; i < D; i += 64)
    out[(size_t)row * D + i] = f2b(x[i] * r * w[i]);
}

// ---------------- attention scores+softmax, two-pass, register scores ----------
#define KVB 128
__global__ __launch_bounds__(512, 2) void k_attn2(const unsigned short* __restrict__ Qcat,
                                                  const unsigned short* __restrict__ Kcat,
                                                  float* __restrict__ attn_out) {
  __shared__ unsigned short Ks[KVB * 192];   // 48 KB
  const int d = blockIdx.x;
  const int xcd = d & 7, i = d >> 3;
  const int bh = xcd | ((i >> 3) << 3);
  const int qc = i & 7;

  const int tid = threadIdx.x, wave = tid >> 6, lane = tid & 63;
  const int l16 = lane & 15, kg = lane >> 4;
  const int qw = qc * 128 + wave * 16;

  const unsigned short* Qb = Qcat + ((size_t)bh * S_ + qw) * CATD;
  s16x8 qf[6];
#pragma unroll
  for (int ks = 0; ks < 6; ++ks)
    qf[ks] = *reinterpret_cast<const s16x8*>(Qb + (size_t)l16 * CATD + ks * 32 + kg * 8);

  int srow[6], scol[6];
#pragma unroll
  for (int j = 0; j < 6; ++j) {
    const int s = j * 512 + tid;
    srow[j] = s / 24;
    scol[j] = ((s % 24) ^ (srow[j] & 7)) * 8;
  }
  const unsigned short* Kb = Kcat + (size_t)bh * S_ * CATD;

  float mx = -1e30f, sm = 0.f, rl = 0.f;

  for (int pass = 0; pass < 2; ++pass) {
    for (int ch = 0; ch < S_ / KVB; ++ch) {
      __syncthreads();
      const unsigned short* Kc = Kb + (size_t)ch * KVB * CATD;
#pragma unroll
      for (int j = 0; j < 6; ++j)
        gl_lds16(Kc + (size_t)srow[j] * CATD + scol[j], (void*)&Ks[(j * 512 + tid) * 8]);
      __syncthreads();

      f32x4 acc[8] = {};
#pragma unroll
      for (int ni = 0; ni < 8; ++ni) {
        const int row = ni * 16 + l16;
#pragma unroll
        for (int ks = 0; ks < 6; ++ks) {
          const int slot = (ks * 4 + kg) ^ (l16 & 7);
          const s16x8 af = *reinterpret_cast<const s16x8*>(&Ks[row * 192 + slot * 8]);
          acc[ni] = mfma16(af, qf[ks], acc[ni]);
        }
      }

      if (pass == 0) {
        float cm = -1e30f;
#pragma unroll
        for (int ni = 0; ni < 8; ++ni)
#pragma unroll
          for (int j = 0; j < 4; ++j) cm = fmaxf(cm, acc[ni][j]);
        const float nm = fmaxf(mx, cm);
        sm *= __expf(mx - nm);
#pragma unroll
        for (int ni = 0; ni < 8; ++ni)
#pragma unroll
          for (int j = 0; j < 4; ++j) sm += __expf(acc[ni][j] - nm);
        mx = nm;
      } else {
        float* Ao = attn_out + ((size_t)bh * S_ + qw + l16) * S_ + ch * KVB;
#pragma unroll
        for (int ni = 0; ni < 8; ++ni) {
          float4 w4;
          w4.x = __expf(acc[ni][0] - mx) * rl;
          w4.y = __expf(acc[ni][1] - mx) * rl;
          w4.z = __expf(acc[ni][2] - mx) * rl;
          w4.w = __expf(acc[ni][3] - mx) * rl;
          *reinterpret_cast<float4*>(Ao + ni * 16 + kg * 4) = w4;
        }
      }
    }
    if (pass == 0) {
#pragma unroll
      for (int off = 16; off < 64; off <<= 1) {
        const float om = __shfl_xor(mx, off, 64);
        const float os = __shfl_xor(sm, off, 64);
        const float nm = fmaxf(mx, om);
        sm = sm * __expf(mx - nm) + os * __expf(om - nm);
        mx = nm;
      }
      rl = 1.0f / sm;
    }
  }
}

// ---------------- PV: batched GEMM ctx[bh] = attn[bh] @ VT[bh]^T, bf16 out ------
__global__ __launch_bounds__(256) void k_pv(const float* __restrict__ attn,
                                            const unsigned short* __restrict__ VT,
                                            unsigned short* __restrict__ ctx) {
  __shared__ unsigned short As[128 * 40];
  __shared__ unsigned short Bs[128 * 32];
  const int bh = blockIdx.z, b = bh >> 4, h = bh & 15;
  const int tm = blockIdx.x * 128;
  const int tid = threadIdx.x;
  const int wave = tid >> 6, lane = tid & 63;
  const int wr = (wave >> 1) * 64, wc = (wave & 1) * 64;
  const int l16 = lane & 15, kg = lane >> 4;
  const int r0s = tid >> 2, c0s = (tid & 3) * 8;
  const int ra = tid >> 1, ha = (tid & 1) * 16;

  const float* Ag = attn + ((size_t)bh * S_ + tm) * S_;
  const unsigned short* Bg = VT + (size_t)bh * HD_ * S_;
  f32x4 acc[4][4] = {};

  for (int k0 = 0; k0 < S_; k0 += 32) {
    __syncthreads();
    const float* Ap = Ag + (size_t)ra * S_ + k0 + ha;
    const float4 v0 = *reinterpret_cast<const float4*>(Ap);
    const float4 v1 = *reinterpret_cast<const float4*>(Ap + 4);
    const float4 v2 = *reinterpret_cast<const float4*>(Ap + 8);
    const float4 v3 = *reinterpret_cast<const float4*>(Ap + 12);
    *reinterpret_cast<s16x8*>(&As[ra * 40 + ha])     = pk8(v0, v1);
    *reinterpret_cast<s16x8*>(&As[ra * 40 + ha + 8]) = pk8(v2, v3);
    gl_lds16(Bg + (size_t)r0s * S_ + k0 + c0s,        (void*)&Bs[tid * 8]);
    gl_lds16(Bg + (size_t)(r0s + 64) * S_ + k0 + c0s, (void*)&Bs[(tid + 256) * 8]);
    __syncthreads();
    s16x8 af[4], bf4[4];
#pragma unroll
    for (int i = 0; i < 4; ++i)
      af[i] = *reinterpret_cast<const s16x8*>(&As[(wr + i * 16 + l16) * 40 + kg * 8]);
#pragma unroll
    for (int i = 0; i < 4; ++i)
      bf4[i] = *reinterpret_cast<const s16x8*>(&Bs[(wc + i * 16 + l16) * 32 + kg * 8]);
#pragma unroll
    for (int mi = 0; mi < 4; ++mi)
#pragma unroll
      for (int ni = 0; ni < 4; ++ni)
        acc[mi][ni] = mfma16(af[mi], bf4[ni], acc[mi][ni]);
  }

#pragma unroll
  for (int mi = 0; mi < 4; ++mi)
#pragma unroll
    for (int ni = 0; ni < 4; ++ni) {
      const int rr = tm + wr + mi * 16 + kg * 4;
      const int cc = wc + ni * 16 + l16;
#pragma unroll
      for (int j = 0; j < 4; ++j)
        ctx[((size_t)(b * S_ + rr + j)) * DM_ + h * HD_ + cc] = f2b(acc[mi][ni][j]);
    }
}

// ---------------- host launch ----------------
extern "C" void kernel_launch(void* const* d_in, const int* in_sizes, int n_in,
                              void* d_out, int out_size, void* d_ws, size_t ws_size,
                              hipStream_t stream) {
  const float* x         = (const float*)d_in[0];
  const float* Wq_down   = (const float*)d_in[1];
  const float* q_norm_w  = (const float*)d_in[2];
  const float* Wq_up     = (const float*)d_in[3];
  const float* Wq_rope   = (const float*)d_in[4];
  const float* Wkv_down  = (const float*)d_in[5];
  const float* kv_norm_w = (const float*)d_in[6];
  const float* Wk_up     = (const float*)d_in[7];
  const float* Wv_up     = (const float*)d_in[8];
  const float* Wk_rope   = (const float*)d_in[9];
  const float* Wout      = (const float*)d_in[10];

  float* out0 = (float*)d_out;
  float* attn = out0 + (size_t)B_ * S_ * DM_;

  char* ws = (char*)d_ws;
  size_t off = 0;
  auto alloc = [&](size_t bytes) -> void* {
    void* p = ws + off;
    off += (bytes + 255) & ~(size_t)255;
    return p;
  };

  unsigned short* xb     = (unsigned short*)alloc((size_t)NTOK * DM_ * 2);
  unsigned short* WdT    = (unsigned short*)alloc((size_t)(DQL_ + DKVL_) * DM_ * 2);
  unsigned short* WrT    = (unsigned short*)alloc((size_t)DM_ * DM_ * 2);
  unsigned short* WqupT  = (unsigned short*)alloc((size_t)DM_ * DQL_ * 2);
  unsigned short* WkvupT = (unsigned short*)alloc((size_t)(2 * DM_) * DKVL_ * 2);
  unsigned short* WoutT  = (unsigned short*)alloc((size_t)DM_ * DM_ * 2);
  float* cdown           = (float*)alloc((size_t)NTOK * (DQL_ + DKVL_) * 4);
  unsigned short* cqb    = (unsigned short*)alloc((size_t)NTOK * DQL_ * 2);
  unsigned short* ckvb   = (unsigned short*)alloc((size_t)NTOK * DKVL_ * 2);
  unsigned short* Qcat   = (unsigned short*)alloc((size_t)B_ * H_ * S_ * CATD * 2);
  unsigned short* Kcat   = (unsigned short*)alloc((size_t)B_ * H_ * S_ * CATD * 2);
  unsigned short* VTb    = (unsigned short*)alloc((size_t)B_ * H_ * HD_ * S_ * 2);
  unsigned short* ctxb   = (unsigned short*)alloc((size_t)NTOK * DM_ * 2);
  float2* csT            = (float2*)alloc((size_t)S_ * 32 * sizeof(float2));

  if (off > ws_size) return;

  const float qsc = 0.07216878364870323f;    // 192^-0.5, folded into Wq_up / Wq_rope

  k_rope_tab<<<128, 256, 0, stream>>>(csT);
  k_f2b<<<(NTOK * DM_ / 4 + 255) / 256, 256, 0, stream>>>(x, xb, NTOK * DM_ / 4);

  TD8 td;
  int blk0 = 0;
  auto setd = [&](int i, const float* in, unsigned short* out, int R, int C, float sc) {
    td.d[i] = TD{in, out, R, C, blk0, sc};
    blk0 += (R >> 6) * (C >> 6);
  };
  setd(0, Wq_down,  WdT,                        DM_,  DQL_,  1.0f);
  setd(1, Wkv_down, WdT + (size_t)DQL_ * DM_,   DM_,  DKVL_, 1.0f);
  setd(2, Wq_rope,  WrT,                        DM_,  1024,  qsc);
  setd(3, Wk_rope,  WrT + (size_t)1024 * DM_,   DM_,  1024,  1.0f);
  setd(4, Wq_up,    WqupT,                      DQL_, DM_,   qsc);
  setd(5, Wk_up,    WkvupT,                     DKVL_, DM_,  1.0f);
  setd(6, Wv_up,    WkvupT + (size_t)DM_ * DKVL_, DKVL_, DM_, 1.0f);
  setd(7, Wout,     WoutT,                      DM_,  DM_,   1.0f);
  k_transpose_all<<<blk0, 256, 0, stream>>>(td);

  // launch 1: down + rope (A = xb)
  k_proj_a<<<368, 256, 0, stream>>>(xb, WdT, WrT, cdown, Qcat, Kcat, csT);
  k_rmsnorm<<<NTOK, 64, 0, stream>>>(cdown,        DQL_ + DKVL_, q_norm_w,  cqb,  DQL_);
  k_rmsnorm<<<NTOK, 64, 0, stream>>>(cdown + DQL_, DQL_ + DKVL_, kv_norm_w, ckvb, DKVL_);

  // launch 2: q-up + kv-up (epilogues write Qcat/Kcat/VT directly)
  k_proj_b<<<768, 256, 0, stream>>>(cqb, ckvb, WqupT, WkvupT, Qcat, Kcat, VTb);

  // attention
  k_attn2<<<256, 512, 0, stream>>>(Qcat, Kcat, attn);
  k_pv<<<dim3(S_ / 128, 1, B_ * H_), 256, 0, stream>>>(attn, VTb, ctxb);

  // output projection
  k_gemm<<<dim3(NTOK / 128, DM_ / 128), 256, 0, stream>>>(ctxb, WoutT, out0, NTOK, DM_, DM_);
}

// Round 5
// 226.492 us; speedup vs baseline: 2.2766x; 1.2007x over previous
//
#include <hip/hip_runtime.h>

#define B_    2
#define S_    1024
#define DM_   2048
#define H_    16
#define HD_   128
#define RD_   64
#define DQL_  384
#define DKVL_ 512
#define NTOK  (B_*S_)
#define CATD  (HD_+RD_)
#define LDSZ  (128*64)

typedef float f32x4 __attribute__((ext_vector_type(4)));
typedef short s16x8 __attribute__((ext_vector_type(8)));
typedef unsigned int u32;

__device__ __forceinline__ unsigned short f2b(float f) {   // fp32 -> bf16 RNE
  u32 u = __float_as_uint(f);
  u = (u + 0x7FFFu + ((u >> 16) & 1u)) >> 16;
  return (unsigned short)u;
}
__device__ __forceinline__ f32x4 mfma16(s16x8 a, s16x8 b, f32x4 c) {
  return __builtin_amdgcn_mfma_f32_16x16x32_bf16(a, b, c, 0, 0, 0);
}
__device__ __forceinline__ void gl_lds16(const void* g, void* l) {
  __builtin_amdgcn_global_load_lds((const __attribute__((address_space(1))) u32*)g,
                                   (__attribute__((address_space(3))) u32*)l, 16, 0, 0);
}
__device__ __forceinline__ s16x8 pk8(float4 a, float4 b) {
  s16x8 r;
  r[0]=(short)f2b(a.x); r[1]=(short)f2b(a.y); r[2]=(short)f2b(a.z); r[3]=(short)f2b(a.w);
  r[4]=(short)f2b(b.x); r[5]=(short)f2b(b.y); r[6]=(short)f2b(b.z); r[7]=(short)f2b(b.w);
  return r;
}

// ---- shared 2-phase prefetch GEMM core: acc += A(128xK) @ Bt(128xK)^T ----
// BK=64 double-buffered. LDS layout: granule slot = row*8 + (colg ^ (row&7)),
// achieved by pre-swizzling the GLOBAL source (gl_lds dest must be linear).
__device__ __forceinline__ void gemm_core(const unsigned short* __restrict__ Ag,
                                          const unsigned short* __restrict__ Bg,
                                          int K,
                                          unsigned short (&As)[2][LDSZ],
                                          unsigned short (&Bs)[2][LDSZ],
                                          f32x4 (&acc)[4][4]) {
  const int tid = threadIdx.x;
  const int wave = tid >> 6, lane = tid & 63;
  const int wr = (wave >> 1) * 64, wc = (wave & 1) * 64;
  const int l16 = lane & 15, kg = lane >> 4;
  int sr[4], sc[4];
#pragma unroll
  for (int i = 0; i < 4; ++i) {
    const int g = i * 256 + tid;
    sr[i] = g >> 3;
    sc[i] = ((g & 7) ^ (sr[i] & 7)) * 8;
  }
  auto STAGE = [&](int b, int k0) {
#pragma unroll
    for (int i = 0; i < 4; ++i) {
      gl_lds16(Ag + (size_t)sr[i] * K + k0 + sc[i], (void*)&As[b][(i * 256 + tid) * 8]);
      gl_lds16(Bg + (size_t)sr[i] * K + k0 + sc[i], (void*)&Bs[b][(i * 256 + tid) * 8]);
    }
  };
  STAGE(0, 0);
  int cur = 0;
  for (int k0 = 0; k0 < K; k0 += 64) {
    __syncthreads();                       // buf[cur] staged; all reads of buf[cur^1] done
    if (k0 + 64 < K) STAGE(cur ^ 1, k0 + 64);
#pragma unroll
    for (int kk = 0; kk < 2; ++kk) {
      const int sl = ((kk * 4 + kg) ^ (l16 & 7)) * 8;
      s16x8 af[4], bf4[4];
#pragma unroll
      for (int i = 0; i < 4; ++i)
        af[i] = *reinterpret_cast<const s16x8*>(&As[cur][(wr + i * 16 + l16) * 64 + sl]);
#pragma unroll
      for (int i = 0; i < 4; ++i)
        bf4[i] = *reinterpret_cast<const s16x8*>(&Bs[cur][(wc + i * 16 + l16) * 64 + sl]);
#pragma unroll
      for (int mi = 0; mi < 4; ++mi)
#pragma unroll
        for (int ni = 0; ni < 4; ++ni)
          acc[mi][ni] = mfma16(af[mi], bf4[ni], acc[mi][ni]);
    }
    cur ^= 1;
  }
}

// ---------------- rope cos/sin table ----------------
__global__ __launch_bounds__(256) void k_rope_tab(float2* __restrict__ csT) {
  const int i = blockIdx.x * 256 + threadIdx.x;
  const int s = i >> 5, p = i & 31;
  const float freq = powf(10000.0f, -(float)p / 32.0f);
  float sn, cs;
  sincosf((float)s * freq, &sn, &cs);
  csT[i] = make_float2(cs, sn);
}

// ---------------- fp32 -> bf16 elementwise ----------------
__global__ __launch_bounds__(256) void k_f2b(const float* __restrict__ in,
                                             unsigned short* __restrict__ out, int n4) {
  int i = blockIdx.x * 256 + threadIdx.x;
  if (i >= n4) return;
  const float4 v = reinterpret_cast<const float4*>(in)[i];
  ushort4 o;
  o.x = f2b(v.x); o.y = f2b(v.y); o.z = f2b(v.z); o.w = f2b(v.w);
  reinterpret_cast<ushort4*>(out)[i] = o;
}

// ---------------- fused transpose-convert of all weights ----------------
struct TD { const float* in; unsigned short* out; int R, C, blk0; float scale; };
struct TD8 { TD d[8]; };
__global__ __launch_bounds__(256) void k_transpose_all(TD8 descs) {
  __shared__ float tile[64][65];
  const int bid = blockIdx.x;
  int di = 0;
#pragma unroll
  for (int i = 1; i < 8; ++i) if (bid >= descs.d[i].blk0) di = i;
  const TD dd = descs.d[di];
  const int local = bid - dd.blk0;
  const int tiles_r = dd.R >> 6;
  const int tr_ = local % tiles_r, tc_ = local / tiles_r;
  const int r0 = tr_ * 64, c0 = tc_ * 64;
  const int t = threadIdx.x;
  const int tr = t >> 4, tc4 = (t & 15) * 4;
#pragma unroll
  for (int i = 0; i < 4; ++i) {
    const int rr = tr + i * 16;
    const float4 v = *reinterpret_cast<const float4*>(dd.in + (size_t)(r0 + rr) * dd.C + c0 + tc4);
    tile[rr][tc4 + 0] = v.x; tile[rr][tc4 + 1] = v.y;
    tile[rr][tc4 + 2] = v.z; tile[rr][tc4 + 3] = v.w;
  }
  __syncthreads();
#pragma unroll
  for (int i = 0; i < 4; ++i) {
    const int oc = tr + i * 16;
    ushort4 o;
    o.x = f2b(tile[tc4 + 0][oc] * dd.scale); o.y = f2b(tile[tc4 + 1][oc] * dd.scale);
    o.z = f2b(tile[tc4 + 2][oc] * dd.scale); o.w = f2b(tile[tc4 + 3][oc] * dd.scale);
    *reinterpret_cast<ushort4*>(dd.out + (size_t)(c0 + oc) * dd.R + r0 + tc4) = o;
  }
}

// ---------------- generic GEMM (Wout): C(MxN,f32) = A @ Bt^T ----------------
__global__ __launch_bounds__(256) void k_gemm2(const unsigned short* __restrict__ A,
                                               const unsigned short* __restrict__ Bt,
                                               float* __restrict__ C,
                                               int M, int N, int K) {
  __shared__ unsigned short As[2][LDSZ];
  __shared__ unsigned short Bs[2][LDSZ];
  const int nwg = gridDim.x * gridDim.y;
  int id = blockIdx.y * gridDim.x + blockIdx.x;
  id = (id & 7) * (nwg >> 3) + (id >> 3);
  const int tm = (id % gridDim.x) * 128;
  const int tn = (id / gridDim.x) * 128;
  const int tid = threadIdx.x;
  const int wave = tid >> 6, lane = tid & 63;
  const int wr = (wave >> 1) * 64, wc = (wave & 1) * 64;
  const int l16 = lane & 15, kg = lane >> 4;

  f32x4 acc[4][4] = {};
  gemm_core(A + (size_t)tm * K, Bt + (size_t)tn * K, K, As, Bs, acc);

#pragma unroll
  for (int mi = 0; mi < 4; ++mi)
#pragma unroll
    for (int ni = 0; ni < 4; ++ni) {
      const int rr = tm + wr + mi * 16 + kg * 4;
      const int cc = tn + wc + ni * 16 + l16;
#pragma unroll
      for (int j = 0; j < 4; ++j)
        C[(size_t)(rr + j) * N + cc] = acc[mi][ni][j];
    }
}

// ---------------- launch 1: A=xb. down(N=896)->cdown ; rope(N=2048)->Qcat/Kcat --
__global__ __launch_bounds__(256) void k_proj_a(const unsigned short* __restrict__ xb,
                                                const unsigned short* __restrict__ WdT,
                                                const unsigned short* __restrict__ WrT,
                                                float* __restrict__ cdown,
                                                unsigned short* __restrict__ Qcat,
                                                unsigned short* __restrict__ Kcat,
                                                const float2* __restrict__ csT) {
  __shared__ unsigned short As[2][LDSZ];
  __shared__ unsigned short Bs[2][LDSZ];
  int id = blockIdx.x;                       // 368 blocks
  id = (id & 7) * 46 + (id >> 3);
  const bool down = id < 112;
  int gm, tn; const unsigned short* Bt;
  if (down) { gm = id % 16; tn = (id / 16) * 128; Bt = WdT; }
  else { const int i2 = id - 112; gm = i2 % 16; tn = (i2 / 16) * 128; Bt = WrT; }
  const int tm = gm * 128;

  const int tid = threadIdx.x;
  const int wave = tid >> 6, lane = tid & 63;
  const int wr = (wave >> 1) * 64, wc = (wave & 1) * 64;
  const int l16 = lane & 15, kg = lane >> 4;

  f32x4 acc[4][4] = {};
  gemm_core(xb + (size_t)tm * DM_, Bt + (size_t)tn * DM_, DM_, As, Bs, acc);

  if (down) {
#pragma unroll
    for (int mi = 0; mi < 4; ++mi)
#pragma unroll
      for (int ni = 0; ni < 4; ++ni) {
        const int rr = tm + wr + mi * 16 + kg * 4;
        const int cc = tn + wc + ni * 16 + l16;
#pragma unroll
        for (int j = 0; j < 4; ++j)
          cdown[(size_t)(rr + j) * (DQL_ + DKVL_) + cc] = acc[mi][ni][j];
      }
  } else {
#pragma unroll
    for (int mi = 0; mi < 4; ++mi)
#pragma unroll
      for (int ni = 0; ni < 4; ++ni) {
        const int col = tn + wc + ni * 16 + l16;
        unsigned short* dst = (col < 1024) ? Qcat : Kcat;
        const int c1 = col & 1023;
        const int hh = c1 >> 6, dd2 = c1 & 63, p = dd2 >> 1, odd = dd2 & 1;
        const int row0 = tm + wr + mi * 16 + kg * 4;
#pragma unroll
        for (int j = 0; j < 4; ++j) {
          const float own = acc[mi][ni][j];
          const float prt = __shfl_xor(own, 1, 64);
          const int tok = row0 + j, b = tok >> 10, s = tok & 1023;
          const float2 cs = csT[s * 32 + p];
          const float o = odd ? (prt * cs.y + own * cs.x) : (own * cs.x - prt * cs.y);
          dst[((size_t)(b * H_ + hh) * S_ + s) * CATD + HD_ + dd2] = f2b(o);
        }
      }
  }
}

// ---------------- launch 2: q-up + kv-up, epilogue -> Qcat/Kcat/VT ----------
__global__ __launch_bounds__(256) void k_proj_b(const unsigned short* __restrict__ cqb,
                                                const unsigned short* __restrict__ ckvb,
                                                const unsigned short* __restrict__ WqupT,
                                                const unsigned short* __restrict__ WkvupT,
                                                unsigned short* __restrict__ Qcat,
                                                unsigned short* __restrict__ Kcat,
                                                unsigned short* __restrict__ VTb) {
  __shared__ unsigned short As[2][LDSZ];
  __shared__ unsigned short Bs[2][LDSZ];
  int id = blockIdx.x;                       // 768 blocks
  id = (id & 7) * 96 + (id >> 3);
  const bool qgrp = id < 256;
  int gm, tn, K; const unsigned short* Bt; const unsigned short* A;
  if (qgrp) { gm = id & 15; tn = (id >> 4) * 128; Bt = WqupT; A = cqb; K = DQL_; }
  else { const int i2 = id - 256; gm = i2 & 15; tn = (i2 >> 4) * 128; Bt = WkvupT; A = ckvb; K = DKVL_; }
  const int tm = gm * 128;

  const int tid = threadIdx.x;
  const int wave = tid >> 6, lane = tid & 63;
  const int wr = (wave >> 1) * 64, wc = (wave & 1) * 64;
  const int l16 = lane & 15, kg = lane >> 4;

  f32x4 acc[4][4] = {};
  gemm_core(A + (size_t)tm * K, Bt + (size_t)tn * K, K, As, Bs, acc);

#pragma unroll
  for (int mi = 0; mi < 4; ++mi)
#pragma unroll
    for (int ni = 0; ni < 4; ++ni) {
      const int col = tn + wc + ni * 16 + l16;
      const int row0 = tm + wr + mi * 16 + kg * 4;
      if (qgrp || col < 2048) {
        unsigned short* dst = qgrp ? Qcat : Kcat;
        const int hh = (col & 2047) >> 7, d = col & 127;
#pragma unroll
        for (int j = 0; j < 4; ++j) {
          const int tok = row0 + j, b = tok >> 10, s = tok & 1023;
          dst[((size_t)(b * H_ + hh) * S_ + s) * CATD + d] = f2b(acc[mi][ni][j]);
        }
      } else {
        const int m2 = col - 2048;
        const int hh = m2 >> 7, d = m2 & 127;
        const int b = row0 >> 10, s0 = row0 & 1023;
        ushort4 o;
        o.x = f2b(acc[mi][ni][0]); o.y = f2b(acc[mi][ni][1]);
        o.z = f2b(acc[mi][ni][2]); o.w = f2b(acc[mi][ni][3]);
        *reinterpret_cast<ushort4*>(&VTb[((size_t)(b * H_ + hh) * HD_ + d) * S_ + s0]) = o;
      }
    }
}

// ---------------- RMSNorm (strided input) ----------------
__global__ __launch_bounds__(64) void k_rmsnorm(const float* __restrict__ in, int stride,
                                                const float* __restrict__ w,
                                                unsigned short* __restrict__ out, int D) {
  const int row = blockIdx.x;
  const float* x = in + (size_t)row * stride;
  float ss = 0.f;
  for (int i = threadIdx.x; i < D; i += 64) { const float v = x[i]; ss = fmaf(v, v, ss); }
#pragma unroll
  for (int off = 32; off; off >>= 1) ss += __shfl_xor(ss, off, 64);
  const float r = rsqrtf(ss / (float)D + 1e-6f);
  for (int i = threadIdx.x; i < D; i += 64)
    out[(size_t)row * D + i] = f2b(x[i] * r * w[i]);
}

// ---------------- attention scores+softmax, two-pass, dbuf KVB=64 ----------
#define KVB 64
__global__ __launch_bounds__(512, 2) void k_attn2(const unsigned short* __restrict__ Qcat,
                                                  const unsigned short* __restrict__ Kcat,
                                                  float* __restrict__ attn_out) {
  __shared__ unsigned short Ks[2][KVB * 192];   // 2 x 24 KB
  const int d = blockIdx.x;
  const int xcd = d & 7, i = d >> 3;
  const int bh = xcd | ((i >> 3) << 3);
  const int qc = i & 7;

  const int tid = threadIdx.x, wave = tid >> 6, lane = tid & 63;
  const int l16 = lane & 15, kg = lane >> 4;
  const int qw = qc * 128 + wave * 16;

  const unsigned short* Qb = Qcat + ((size_t)bh * S_ + qw) * CATD;
  s16x8 qf[6];
#pragma unroll
  for (int ks = 0; ks < 6; ++ks)
    qf[ks] = *reinterpret_cast<const s16x8*>(Qb + (size_t)l16 * CATD + ks * 32 + kg * 8);

  int sr[3], sc[3];
#pragma unroll
  for (int j = 0; j < 3; ++j) {
    const int s = j * 512 + tid;
    sr[j] = s / 24;
    sc[j] = ((s % 24) ^ (sr[j] & 7)) * 8;
  }
  const unsigned short* Kb = Kcat + (size_t)bh * S_ * CATD;
  auto STAGE = [&](int b, int ch) {
    const unsigned short* Kc = Kb + (size_t)ch * KVB * CATD;
#pragma unroll
    for (int j = 0; j < 3; ++j)
      gl_lds16(Kc + (size_t)sr[j] * CATD + sc[j], (void*)&Ks[b][(j * 512 + tid) * 8]);
  };

  STAGE(0, 0);
  float mx = -1e30f, sm = 0.f, rl = 0.f;
  int cur = 0;

  for (int g = 0; g < 32; ++g) {
    __syncthreads();                        // buf[cur] ready
    if (g < 31) STAGE(cur ^ 1, (g + 1) & 15);
    const int ch = g & 15;

    f32x4 acc[4] = {};
#pragma unroll
    for (int ni = 0; ni < 4; ++ni) {
      const int row = ni * 16 + l16;
#pragma unroll
      for (int ks = 0; ks < 6; ++ks) {
        const int slot = (ks * 4 + kg) ^ (l16 & 7);
        const s16x8 af = *reinterpret_cast<const s16x8*>(&Ks[cur][row * 192 + slot * 8]);
        acc[ni] = mfma16(af, qf[ks], acc[ni]);
      }
    }

    if (g < 16) {
      float cm = -1e30f;
#pragma unroll
      for (int ni = 0; ni < 4; ++ni)
#pragma unroll
        for (int j = 0; j < 4; ++j) cm = fmaxf(cm, acc[ni][j]);
      const float nm = fmaxf(mx, cm);
      sm *= __expf(mx - nm);
#pragma unroll
      for (int ni = 0; ni < 4; ++ni)
#pragma unroll
        for (int j = 0; j < 4; ++j) sm += __expf(acc[ni][j] - nm);
      mx = nm;
      if (g == 15) {
#pragma unroll
        for (int off = 16; off < 64; off <<= 1) {
          const float om = __shfl_xor(mx, off, 64);
          const float os = __shfl_xor(sm, off, 64);
          const float nm2 = fmaxf(mx, om);
          sm = sm * __expf(mx - nm2) + os * __expf(om - nm2);
          mx = nm2;
        }
        rl = 1.0f / sm;
      }
    } else {
      float* Ao = attn_out + ((size_t)bh * S_ + qw + l16) * S_ + ch * KVB;
#pragma unroll
      for (int ni = 0; ni < 4; ++ni) {
        float4 w4;
        w4.x = __expf(acc[ni][0] - mx) * rl;
        w4.y = __expf(acc[ni][1] - mx) * rl;
        w4.z = __expf(acc[ni][2] - mx) * rl;
        w4.w = __expf(acc[ni][3] - mx) * rl;
        *reinterpret_cast<float4*>(Ao + ni * 16 + kg * 4) = w4;
      }
    }
    cur ^= 1;
  }
}

// ---------------- PV: ctx[bh] = attn[bh] @ VT[bh]^T, dbuf BK=64 ----------------
__global__ __launch_bounds__(256) void k_pv(const float* __restrict__ attn,
                                            const unsigned short* __restrict__ VT,
                                            unsigned short* __restrict__ ctx) {
  __shared__ unsigned short As[2][LDSZ];
  __shared__ unsigned short Bs[2][LDSZ];
  const int bh = blockIdx.z, b = bh >> 4, h = bh & 15;
  const int tm = blockIdx.x * 128;
  const int tid = threadIdx.x;
  const int wave = tid >> 6, lane = tid & 63;
  const int wr = (wave >> 1) * 64, wc = (wave & 1) * 64;
  const int l16 = lane & 15, kg = lane >> 4;

  const float* Ag = attn + ((size_t)bh * S_ + tm) * S_;
  const unsigned short* Bg = VT + (size_t)bh * HD_ * S_;

  // A staging (fp32->bf16 reg-staged, swizzled ds_write): thread q-th granule:
  // row = q*32 + tid>>3, colg = tid&7  -> slot = row*8 + (colg ^ (row&7))
  const int acg = tid & 7;
  int ar[4];
#pragma unroll
  for (int q = 0; q < 4; ++q) ar[q] = q * 32 + (tid >> 3);
  // B staging via gl_lds16 pre-swizzled source
  int sr[4], sc[4];
#pragma unroll
  for (int i = 0; i < 4; ++i) {
    const int g = i * 256 + tid;
    sr[i] = g >> 3;
    sc[i] = ((g & 7) ^ (sr[i] & 7)) * 8;
  }
  auto STAGE = [&](int bb, int k0) {
#pragma unroll
    for (int i = 0; i < 4; ++i)
      gl_lds16(Bg + (size_t)sr[i] * S_ + k0 + sc[i], (void*)&Bs[bb][(i * 256 + tid) * 8]);
#pragma unroll
    for (int q = 0; q < 4; ++q) {
      const float* p = Ag + (size_t)ar[q] * S_ + k0 + acg * 8;
      const float4 v0 = *reinterpret_cast<const float4*>(p);
      const float4 v1 = *reinterpret_cast<const float4*>(p + 4);
      const int slot = ar[q] * 8 + (acg ^ (ar[q] & 7));
      *reinterpret_cast<s16x8*>(&As[bb][slot * 8]) = pk8(v0, v1);
    }
  };

  STAGE(0, 0);
  f32x4 acc[4][4] = {};
  int cur = 0;
  for (int k0 = 0; k0 < S_; k0 += 64) {
    __syncthreads();
    if (k0 + 64 < S_) STAGE(cur ^ 1, k0 + 64);
#pragma unroll
    for (int kk = 0; kk < 2; ++kk) {
      const int sl = ((kk * 4 + kg) ^ (l16 & 7)) * 8;
      s16x8 af[4], bf4[4];
#pragma unroll
      for (int i = 0; i < 4; ++i)
        af[i] = *reinterpret_cast<const s16x8*>(&As[cur][(wr + i * 16 + l16) * 64 + sl]);
#pragma unroll
      for (int i = 0; i < 4; ++i)
        bf4[i] = *reinterpret_cast<const s16x8*>(&Bs[cur][(wc + i * 16 + l16) * 64 + sl]);
#pragma unroll
      for (int mi = 0; mi < 4; ++mi)
#pragma unroll
        for (int ni = 0; ni < 4; ++ni)
          acc[mi][ni] = mfma16(af[mi], bf4[ni], acc[mi][ni]);
    }
    cur ^= 1;
  }

#pragma unroll
  for (int mi = 0; mi < 4; ++mi)
#pragma unroll
    for (int ni = 0; ni < 4; ++ni) {
      const int rr = tm + wr + mi * 16 + kg * 4;
      const int cc = wc + ni * 16 + l16;
#pragma unroll
      for (int j = 0; j < 4; ++j)
        ctx[((size_t)(b * S_ + rr + j)) * DM_ + h * HD_ + cc] = f2b(acc[mi][ni][j]);
    }
}

// ---------------- host launch ----------------
extern "C" void kernel_launch(void* const* d_in, const int* in_sizes, int n_in,
                              void* d_out, int out_size, void* d_ws, size_t ws_size,
                              hipStream_t stream) {
  const float* x         = (const float*)d_in[0];
  const float* Wq_down   = (const float*)d_in[1];
  const float* q_norm_w  = (const float*)d_in[2];
  const float* Wq_up     = (const float*)d_in[3];
  const float* Wq_rope   = (const float*)d_in[4];
  const float* Wkv_down  = (const float*)d_in[5];
  const float* kv_norm_w = (const float*)d_in[6];
  const float* Wk_up     = (const float*)d_in[7];
  const float* Wv_up     = (const float*)d_in[8];
  const float* Wk_rope   = (const float*)d_in[9];
  const float* Wout      = (const float*)d_in[10];

  float* out0 = (float*)d_out;
  float* attn = out0 + (size_t)B_ * S_ * DM_;

  char* ws = (char*)d_ws;
  size_t off = 0;
  auto alloc = [&](size_t bytes) -> void* {
    void* p = ws + off;
    off += (bytes + 255) & ~(size_t)255;
    return p;
  };

  unsigned short* xb     = (unsigned short*)alloc((size_t)NTOK * DM_ * 2);
  unsigned short* WdT    = (unsigned short*)alloc((size_t)(DQL_ + DKVL_) * DM_ * 2);
  unsigned short* WrT    = (unsigned short*)alloc((size_t)DM_ * DM_ * 2);
  unsigned short* WqupT  = (unsigned short*)alloc((size_t)DM_ * DQL_ * 2);
  unsigned short* WkvupT = (unsigned short*)alloc((size_t)(2 * DM_) * DKVL_ * 2);
  unsigned short* WoutT  = (unsigned short*)alloc((size_t)DM_ * DM_ * 2);
  float* cdown           = (float*)alloc((size_t)NTOK * (DQL_ + DKVL_) * 4);
  unsigned short* cqb    = (unsigned short*)alloc((size_t)NTOK * DQL_ * 2);
  unsigned short* ckvb   = (unsigned short*)alloc((size_t)NTOK * DKVL_ * 2);
  unsigned short* Qcat   = (unsigned short*)alloc((size_t)B_ * H_ * S_ * CATD * 2);
  unsigned short* Kcat   = (unsigned short*)alloc((size_t)B_ * H_ * S_ * CATD * 2);
  unsigned short* VTb    = (unsigned short*)alloc((size_t)B_ * H_ * HD_ * S_ * 2);
  unsigned short* ctxb   = (unsigned short*)alloc((size_t)NTOK * DM_ * 2);
  float2* csT            = (float2*)alloc((size_t)S_ * 32 * sizeof(float2));

  if (off > ws_size) return;

  const float qsc = 0.07216878364870323f;    // 192^-0.5 folded into Wq_up / Wq_rope

  k_rope_tab<<<128, 256, 0, stream>>>(csT);
  k_f2b<<<(NTOK * DM_ / 4 + 255) / 256, 256, 0, stream>>>(x, xb, NTOK * DM_ / 4);

  TD8 td;
  int blk0 = 0;
  auto setd = [&](int i, const float* in, unsigned short* out, int R, int C, float sc) {
    td.d[i] = TD{in, out, R, C, blk0, sc};
    blk0 += (R >> 6) * (C >> 6);
  };
  setd(0, Wq_down,  WdT,                        DM_,  DQL_,  1.0f);
  setd(1, Wkv_down, WdT + (size_t)DQL_ * DM_,   DM_,  DKVL_, 1.0f);
  setd(2, Wq_rope,  WrT,                        DM_,  1024,  qsc);
  setd(3, Wk_rope,  WrT + (size_t)1024 * DM_,   DM_,  1024,  1.0f);
  setd(4, Wq_up,    WqupT,                      DQL_, DM_,   qsc);
  setd(5, Wk_up,    WkvupT,                     DKVL_, DM_,  1.0f);
  setd(6, Wv_up,    WkvupT + (size_t)DM_ * DKVL_, DKVL_, DM_, 1.0f);
  setd(7, Wout,     WoutT,                      DM_,  DM_,   1.0f);
  k_transpose_all<<<blk0, 256, 0, stream>>>(td);

  k_proj_a<<<368, 256, 0, stream>>>(xb, WdT, WrT, cdown, Qcat, Kcat, csT);
  k_rmsnorm<<<NTOK, 64, 0, stream>>>(cdown,        DQL_ + DKVL_, q_norm_w,  cqb,  DQL_);
  k_rmsnorm<<<NTOK, 64, 0, stream>>>(cdown + DQL_, DQL_ + DKVL_, kv_norm_w, ckvb, DKVL_);

  k_proj_b<<<768, 256, 0, stream>>>(cqb, ckvb, WqupT, WkvupT, Qcat, Kcat, VTb);

  k_attn2<<<256, 512, 0, stream>>>(Qcat, Kcat, attn);
  k_pv<<<dim3(S_ / 128, 1, B_ * H_), 256, 0, stream>>>(attn, VTb, ctxb);

  k_gemm2<<<dim3(NTOK / 128, DM_ / 128), 256, 0, stream>>>(ctxb, WoutT, out0, NTOK, DM_, DM_);
}

// Round 6
// 211.166 us; speedup vs baseline: 2.4418x; 1.0726x over previous
//
#include <hip/hip_runtime.h>

#define B_    2
#define S_    1024
#define DM_   2048
#define H_    16
#define HD_   128
#define RD_   64
#define DQL_  384
#define DKVL_ 512
#define NTOK  (B_*S_)
#define CATD  (HD_+RD_)
#define LDSZ  (128*64)

typedef float f32x4 __attribute__((ext_vector_type(4)));
typedef short s16x8 __attribute__((ext_vector_type(8)));
typedef unsigned int u32;

__device__ __forceinline__ unsigned short f2b(float f) {   // fp32 -> bf16 RNE
  u32 u = __float_as_uint(f);
  u = (u + 0x7FFFu + ((u >> 16) & 1u)) >> 16;
  return (unsigned short)u;
}
__device__ __forceinline__ f32x4 mfma16(s16x8 a, s16x8 b, f32x4 c) {
  return __builtin_amdgcn_mfma_f32_16x16x32_bf16(a, b, c, 0, 0, 0);
}
__device__ __forceinline__ void gl_lds16(const void* g, void* l) {
  __builtin_amdgcn_global_load_lds((const __attribute__((address_space(1))) u32*)g,
                                   (__attribute__((address_space(3))) u32*)l, 16, 0, 0);
}

// ---- 512-thread 2-phase prefetch GEMM core: acc += A(128xK) @ Bt(128xK)^T ----
// 8 waves (2x4), wave tile 64x32. BK=64 dbuf. XOR-swizzled LDS via pre-swizzled
// global source (rule #21: linear dest + inv-swz source + swz read).
__device__ __forceinline__ void gemm_core(const unsigned short* __restrict__ Ag,
                                          const unsigned short* __restrict__ Bg,
                                          int K,
                                          unsigned short (&As)[2][LDSZ],
                                          unsigned short (&Bs)[2][LDSZ],
                                          f32x4 (&acc)[4][2]) {
  const int tid = threadIdx.x;
  const int wave = tid >> 6, lane = tid & 63;
  const int wr = (wave >> 2) * 64, wc = (wave & 3) * 32;
  const int l16 = lane & 15, kg = lane >> 4;
  int sr[2], sc[2];
#pragma unroll
  for (int i = 0; i < 2; ++i) {
    const int g = i * 512 + tid;
    sr[i] = g >> 3;
    sc[i] = ((g & 7) ^ (sr[i] & 7)) * 8;
  }
  auto STAGE = [&](int b, int k0) {
#pragma unroll
    for (int i = 0; i < 2; ++i) {
      gl_lds16(Ag + (size_t)sr[i] * K + k0 + sc[i], (void*)&As[b][(i * 512 + tid) * 8]);
      gl_lds16(Bg + (size_t)sr[i] * K + k0 + sc[i], (void*)&Bs[b][(i * 512 + tid) * 8]);
    }
  };
  STAGE(0, 0);
  int cur = 0;
  for (int k0 = 0; k0 < K; k0 += 64) {
    __syncthreads();
    if (k0 + 64 < K) STAGE(cur ^ 1, k0 + 64);
#pragma unroll
    for (int kk = 0; kk < 2; ++kk) {
      const int sl = ((kk * 4 + kg) ^ (l16 & 7)) * 8;
      s16x8 af[4], bf2[2];
#pragma unroll
      for (int i = 0; i < 4; ++i)
        af[i] = *reinterpret_cast<const s16x8*>(&As[cur][(wr + i * 16 + l16) * 64 + sl]);
#pragma unroll
      for (int i = 0; i < 2; ++i)
        bf2[i] = *reinterpret_cast<const s16x8*>(&Bs[cur][(wc + i * 16 + l16) * 64 + sl]);
#pragma unroll
      for (int mi = 0; mi < 4; ++mi)
#pragma unroll
        for (int ni = 0; ni < 2; ++ni)
          acc[mi][ni] = mfma16(af[mi], bf2[ni], acc[mi][ni]);
    }
    cur ^= 1;
  }
}

// ---------------- rope cos/sin table ----------------
__global__ __launch_bounds__(256) void k_rope_tab(float2* __restrict__ csT) {
  const int i = blockIdx.x * 256 + threadIdx.x;
  const int s = i >> 5, p = i & 31;
  const float freq = powf(10000.0f, -(float)p / 32.0f);
  float sn, cs;
  sincosf((float)s * freq, &sn, &cs);
  csT[i] = make_float2(cs, sn);
}

// ---------------- fp32 -> bf16 elementwise ----------------
__global__ __launch_bounds__(256) void k_f2b(const float* __restrict__ in,
                                             unsigned short* __restrict__ out, int n4) {
  int i = blockIdx.x * 256 + threadIdx.x;
  if (i >= n4) return;
  const float4 v = reinterpret_cast<const float4*>(in)[i];
  ushort4 o;
  o.x = f2b(v.x); o.y = f2b(v.y); o.z = f2b(v.z); o.w = f2b(v.w);
  reinterpret_cast<ushort4*>(out)[i] = o;
}

// ---------------- fused transpose-convert of all weights ----------------
struct TD { const float* in; unsigned short* out; int R, C, blk0; float scale; };
struct TD8 { TD d[8]; };
__global__ __launch_bounds__(256) void k_transpose_all(TD8 descs) {
  __shared__ float tile[64][65];
  const int bid = blockIdx.x;
  int di = 0;
#pragma unroll
  for (int i = 1; i < 8; ++i) if (bid >= descs.d[i].blk0) di = i;
  const TD dd = descs.d[di];
  const int local = bid - dd.blk0;
  const int tiles_r = dd.R >> 6;
  const int tr_ = local % tiles_r, tc_ = local / tiles_r;
  const int r0 = tr_ * 64, c0 = tc_ * 64;
  const int t = threadIdx.x;
  const int tr = t >> 4, tc4 = (t & 15) * 4;
#pragma unroll
  for (int i = 0; i < 4; ++i) {
    const int rr = tr + i * 16;
    const float4 v = *reinterpret_cast<const float4*>(dd.in + (size_t)(r0 + rr) * dd.C + c0 + tc4);
    tile[rr][tc4 + 0] = v.x; tile[rr][tc4 + 1] = v.y;
    tile[rr][tc4 + 2] = v.z; tile[rr][tc4 + 3] = v.w;
  }
  __syncthreads();
#pragma unroll
  for (int i = 0; i < 4; ++i) {
    const int oc = tr + i * 16;
    ushort4 o;
    o.x = f2b(tile[tc4 + 0][oc] * dd.scale); o.y = f2b(tile[tc4 + 1][oc] * dd.scale);
    o.z = f2b(tile[tc4 + 2][oc] * dd.scale); o.w = f2b(tile[tc4 + 3][oc] * dd.scale);
    *reinterpret_cast<ushort4*>(dd.out + (size_t)(c0 + oc) * dd.R + r0 + tc4) = o;
  }
}

// ---------------- Wout GEMM: C(MxN,f32) = A @ Bt^T ----------------
__global__ __launch_bounds__(512, 2) void k_gemm2(const unsigned short* __restrict__ A,
                                                  const unsigned short* __restrict__ Bt,
                                                  float* __restrict__ C,
                                                  int M, int N, int K) {
  __shared__ unsigned short As[2][LDSZ];
  __shared__ unsigned short Bs[2][LDSZ];
  const int nwg = gridDim.x * gridDim.y;
  int id = blockIdx.y * gridDim.x + blockIdx.x;
  id = (id & 7) * (nwg >> 3) + (id >> 3);
  const int tm = (id % gridDim.x) * 128;
  const int tn = (id / gridDim.x) * 128;
  const int tid = threadIdx.x;
  const int wave = tid >> 6, lane = tid & 63;
  const int wr = (wave >> 2) * 64, wc = (wave & 3) * 32;
  const int l16 = lane & 15, kg = lane >> 4;

  f32x4 acc[4][2] = {};
  gemm_core(A + (size_t)tm * K, Bt + (size_t)tn * K, K, As, Bs, acc);

#pragma unroll
  for (int mi = 0; mi < 4; ++mi)
#pragma unroll
    for (int ni = 0; ni < 2; ++ni) {
      const int rr = tm + wr + mi * 16 + kg * 4;
      const int cc = tn + wc + ni * 16 + l16;
#pragma unroll
      for (int j = 0; j < 4; ++j)
        C[(size_t)(rr + j) * N + cc] = acc[mi][ni][j];
    }
}

// ---------------- launch 1: A=xb. down(N=896)->cdown ; rope(N=2048)->Qcat/Kcat --
__global__ __launch_bounds__(512, 2) void k_proj_a(const unsigned short* __restrict__ xb,
                                                   const unsigned short* __restrict__ WdT,
                                                   const unsigned short* __restrict__ WrT,
                                                   float* __restrict__ cdown,
                                                   unsigned short* __restrict__ Qcat,
                                                   unsigned short* __restrict__ Kcat,
                                                   const float2* __restrict__ csT) {
  __shared__ unsigned short As[2][LDSZ];
  __shared__ unsigned short Bs[2][LDSZ];
  int id = blockIdx.x;                       // 368 blocks
  id = (id & 7) * 46 + (id >> 3);
  const bool down = id < 112;
  int gm, tn; const unsigned short* Bt;
  if (down) { gm = id % 16; tn = (id / 16) * 128; Bt = WdT; }
  else { const int i2 = id - 112; gm = i2 % 16; tn = (i2 / 16) * 128; Bt = WrT; }
  const int tm = gm * 128;

  const int tid = threadIdx.x;
  const int wave = tid >> 6, lane = tid & 63;
  const int wr = (wave >> 2) * 64, wc = (wave & 3) * 32;
  const int l16 = lane & 15, kg = lane >> 4;

  f32x4 acc[4][2] = {};
  gemm_core(xb + (size_t)tm * DM_, Bt + (size_t)tn * DM_, DM_, As, Bs, acc);

  if (down) {
#pragma unroll
    for (int mi = 0; mi < 4; ++mi)
#pragma unroll
      for (int ni = 0; ni < 2; ++ni) {
        const int rr = tm + wr + mi * 16 + kg * 4;
        const int cc = tn + wc + ni * 16 + l16;
#pragma unroll
        for (int j = 0; j < 4; ++j)
          cdown[(size_t)(rr + j) * (DQL_ + DKVL_) + cc] = acc[mi][ni][j];
      }
  } else {
#pragma unroll
    for (int mi = 0; mi < 4; ++mi)
#pragma unroll
      for (int ni = 0; ni < 2; ++ni) {
        const int col = tn + wc + ni * 16 + l16;
        unsigned short* dst = (col < 1024) ? Qcat : Kcat;
        const int c1 = col & 1023;
        const int hh = c1 >> 6, dd2 = c1 & 63, p = dd2 >> 1, odd = dd2 & 1;
        const int row0 = tm + wr + mi * 16 + kg * 4;
#pragma unroll
        for (int j = 0; j < 4; ++j) {
          const float own = acc[mi][ni][j];
          const float prt = __shfl_xor(own, 1, 64);
          const int tok = row0 + j, b = tok >> 10, s = tok & 1023;
          const float2 cs = csT[s * 32 + p];
          const float o = odd ? (prt * cs.y + own * cs.x) : (own * cs.x - prt * cs.y);
          dst[((size_t)(b * H_ + hh) * S_ + s) * CATD + HD_ + dd2] = f2b(o);
        }
      }
  }
}

// ---------------- launch 2: q-up + kv-up, epilogue -> Qcat/Kcat/VT ----------
__global__ __launch_bounds__(512, 2) void k_proj_b(const unsigned short* __restrict__ cqb,
                                                   const unsigned short* __restrict__ ckvb,
                                                   const unsigned short* __restrict__ WqupT,
                                                   const unsigned short* __restrict__ WkvupT,
                                                   unsigned short* __restrict__ Qcat,
                                                   unsigned short* __restrict__ Kcat,
                                                   unsigned short* __restrict__ VTb) {
  __shared__ unsigned short As[2][LDSZ];
  __shared__ unsigned short Bs[2][LDSZ];
  int id = blockIdx.x;                       // 768 blocks
  id = (id & 7) * 96 + (id >> 3);
  const bool qgrp = id < 256;
  int gm, tn, K; const unsigned short* Bt; const unsigned short* A;
  if (qgrp) { gm = id & 15; tn = (id >> 4) * 128; Bt = WqupT; A = cqb; K = DQL_; }
  else { const int i2 = id - 256; gm = i2 & 15; tn = (i2 >> 4) * 128; Bt = WkvupT; A = ckvb; K = DKVL_; }
  const int tm = gm * 128;

  const int tid = threadIdx.x;
  const int wave = tid >> 6, lane = tid & 63;
  const int wr = (wave >> 2) * 64, wc = (wave & 3) * 32;
  const int l16 = lane & 15, kg = lane >> 4;

  f32x4 acc[4][2] = {};
  gemm_core(A + (size_t)tm * K, Bt + (size_t)tn * K, K, As, Bs, acc);

#pragma unroll
  for (int mi = 0; mi < 4; ++mi)
#pragma unroll
    for (int ni = 0; ni < 2; ++ni) {
      const int col = tn + wc + ni * 16 + l16;
      const int row0 = tm + wr + mi * 16 + kg * 4;
      if (qgrp || col < 2048) {
        unsigned short* dst = qgrp ? Qcat : Kcat;
        const int hh = (col & 2047) >> 7, d = col & 127;
#pragma unroll
        for (int j = 0; j < 4; ++j) {
          const int tok = row0 + j, b = tok >> 10, s = tok & 1023;
          dst[((size_t)(b * H_ + hh) * S_ + s) * CATD + d] = f2b(acc[mi][ni][j]);
        }
      } else {
        const int m2 = col - 2048;
        const int hh = m2 >> 7, d = m2 & 127;
        const int b = row0 >> 10, s0 = row0 & 1023;
        ushort4 o;
        o.x = f2b(acc[mi][ni][0]); o.y = f2b(acc[mi][ni][1]);
        o.z = f2b(acc[mi][ni][2]); o.w = f2b(acc[mi][ni][3]);
        *reinterpret_cast<ushort4*>(&VTb[((size_t)(b * H_ + hh) * HD_ + d) * S_ + s0]) = o;
      }
    }
}

// ---------------- RMSNorm (strided input) ----------------
__global__ __launch_bounds__(64) void k_rmsnorm(const float* __restrict__ in, int stride,
                                                const float* __restrict__ w,
                                                unsigned short* __restrict__ out, int D) {
  const int row = blockIdx.x;
  const float* x = in + (size_t)row * stride;
  float ss = 0.f;
  for (int i = threadIdx.x; i < D; i += 64) { const float v = x[i]; ss = fmaf(v, v, ss); }
#pragma unroll
  for (int off = 32; off; off >>= 1) ss += __shfl_xor(ss, off, 64);
  const float r = rsqrtf(ss / (float)D + 1e-6f);
  for (int i = threadIdx.x; i < D; i += 64)
    out[(size_t)row * D + i] = f2b(x[i] * r * w[i]);
}

// ---------------- fused attention: two-pass softmax + attn write + PV ----------
// 256 blocks (32 bh x 8 qc), 512 thr. K dbuf (48K) + V single (16K) + P (16K) = 80K.
#define KVB 64
__global__ __launch_bounds__(512, 4) void k_attn3(const unsigned short* __restrict__ Qcat,
                                                  const unsigned short* __restrict__ Kcat,
                                                  const unsigned short* __restrict__ VT,
                                                  float* __restrict__ attn_out,
                                                  unsigned short* __restrict__ ctx) {
  __shared__ unsigned short Ks[2][KVB * 192];
  __shared__ unsigned short Vs[128 * 64];
  __shared__ unsigned short Pl[8][16 * 64];
  const int d0 = blockIdx.x;
  const int xcd = d0 & 7, i0 = d0 >> 3;
  const int bh = xcd | ((i0 >> 3) << 3);
  const int qc = i0 & 7;
  const int b = bh >> 4, h = bh & 15;

  const int tid = threadIdx.x, wave = tid >> 6, lane = tid & 63;
  const int l16 = lane & 15, kg = lane >> 4;
  const int qw = qc * 128 + wave * 16;

  const unsigned short* Qb = Qcat + ((size_t)bh * S_ + qw) * CATD;
  s16x8 qf[6];
#pragma unroll
  for (int ks = 0; ks < 6; ++ks)
    qf[ks] = *reinterpret_cast<const s16x8*>(Qb + (size_t)l16 * CATD + ks * 32 + kg * 8);

  int srk[3], sck[3];
#pragma unroll
  for (int j = 0; j < 3; ++j) {
    const int s = j * 512 + tid;
    srk[j] = s / 24;
    sck[j] = ((s % 24) ^ (srk[j] & 7)) * 8;
  }
  const unsigned short* Kb = Kcat + (size_t)bh * S_ * CATD;
  auto STAGE_K = [&](int bb, int ch) {
    const unsigned short* Kc = Kb + (size_t)ch * KVB * CATD;
#pragma unroll
    for (int j = 0; j < 3; ++j)
      gl_lds16(Kc + (size_t)srk[j] * CATD + sck[j], (void*)&Ks[bb][(j * 512 + tid) * 8]);
  };

  const unsigned short* Vb = VT + (size_t)bh * HD_ * S_;
  int srv[2], scv[2];
#pragma unroll
  for (int i = 0; i < 2; ++i) {
    const int g = i * 512 + tid;
    srv[i] = g >> 3;
    scv[i] = ((g & 7) ^ (srv[i] & 7)) * 8;
  }
  auto STAGE_V = [&](int ch) {
#pragma unroll
    for (int i = 0; i < 2; ++i)
      gl_lds16(Vb + (size_t)srv[i] * S_ + ch * KVB + scv[i], (void*)&Vs[(i * 512 + tid) * 8]);
  };

  f32x4 oacc[8] = {};
  float mx = -1e30f, sm = 0.f, rl = 0.f;

  STAGE_K(0, 0);
  int cur = 0;
  for (int g = 0; g < 32; ++g) {
    __syncthreads();                        // drains all VMEM: Ks[cur] ready, Vs/Pl consumed
    const int ch = g & 15;
    const bool p2 = g >= 16;
    if (p2) STAGE_V(ch);                    // 2 gl_lds, waited via counted vmcnt below
    if (g < 31) STAGE_K(cur ^ 1, (g + 1) & 15);   // 3 gl_lds, stay in flight across barrier

    f32x4 acc[4] = {};
#pragma unroll
    for (int ni = 0; ni < 4; ++ni) {
      const int row = ni * 16 + l16;
#pragma unroll
      for (int ks = 0; ks < 6; ++ks) {
        const int slot = (ks * 4 + kg) ^ (l16 & 7);
        const s16x8 af = *reinterpret_cast<const s16x8*>(&Ks[cur][row * 192 + slot * 8]);
        acc[ni] = mfma16(af, qf[ks], acc[ni]);
      }
    }

    if (!p2) {
      float cm = -1e30f;
#pragma unroll
      for (int ni = 0; ni < 4; ++ni)
#pragma unroll
        for (int j = 0; j < 4; ++j) cm = fmaxf(cm, acc[ni][j]);
      const float nm = fmaxf(mx, cm);
      sm *= __expf(mx - nm);
#pragma unroll
      for (int ni = 0; ni < 4; ++ni)
#pragma unroll
        for (int j = 0; j < 4; ++j) sm += __expf(acc[ni][j] - nm);
      mx = nm;
      if (g == 15) {                        // combine kg-group partials
#pragma unroll
        for (int off = 16; off < 64; off <<= 1) {
          const float om = __shfl_xor(mx, off, 64);
          const float os = __shfl_xor(sm, off, 64);
          const float nm2 = fmaxf(mx, om);
          sm = sm * __expf(mx - nm2) + os * __expf(om - nm2);
          mx = nm2;
        }
        rl = 1.0f / sm;
      }
    } else {
      // V ready gate: outstanding = 2(V) + 3(K-prefetch) -> wait <=3 keeps K in flight
      if (g < 31) asm volatile("s_waitcnt vmcnt(3)" ::: "memory");
      else        asm volatile("s_waitcnt vmcnt(0)" ::: "memory");
      __builtin_amdgcn_s_barrier();
      __builtin_amdgcn_sched_barrier(0);

      float* Ao = attn_out + ((size_t)bh * S_ + qw + l16) * S_ + ch * KVB;
      unsigned short* Pw = &Pl[wave][0];
#pragma unroll
      for (int ni = 0; ni < 4; ++ni) {
        float4 w4;
        w4.x = __expf(acc[ni][0] - mx) * rl;
        w4.y = __expf(acc[ni][1] - mx) * rl;
        w4.z = __expf(acc[ni][2] - mx) * rl;
        w4.w = __expf(acc[ni][3] - mx) * rl;
        *reinterpret_cast<float4*>(Ao + ni * 16 + kg * 4) = w4;
        ushort4 pb;
        pb.x = f2b(w4.x); pb.y = f2b(w4.y); pb.z = f2b(w4.z); pb.w = f2b(w4.w);
        *reinterpret_cast<ushort4*>(&Pw[l16 * 64 + (((ni * 4 + kg) ^ l16) * 4)]) = pb;
      }
      // PV: A = P (16q x 64k, same-wave LDS bounce), B = V (LDS, swizzled read)
#pragma unroll
      for (int kk = 0; kk < 2; ++kk) {
        const short4 lo = *reinterpret_cast<const short4*>(&Pw[l16 * 64 + (((kk * 8 + kg * 2 + 0) ^ l16) * 4)]);
        const short4 hi = *reinterpret_cast<const short4*>(&Pw[l16 * 64 + (((kk * 8 + kg * 2 + 1) ^ l16) * 4)]);
        s16x8 pa;
        pa[0] = lo.x; pa[1] = lo.y; pa[2] = lo.z; pa[3] = lo.w;
        pa[4] = hi.x; pa[5] = hi.y; pa[6] = hi.z; pa[7] = hi.w;
#pragma unroll
        for (int ni = 0; ni < 8; ++ni) {
          const int row = ni * 16 + l16;
          const s16x8 vf = *reinterpret_cast<const s16x8*>(
              &Vs[row * 64 + (((kk * 4 + kg) ^ (l16 & 7)) * 8)]);
          oacc[ni] = mfma16(pa, vf, oacc[ni]);
        }
      }
    }
    cur ^= 1;
  }

#pragma unroll
  for (int ni = 0; ni < 8; ++ni)
#pragma unroll
    for (int j = 0; j < 4; ++j)
      ctx[((size_t)(b * S_ + qw + kg * 4 + j)) * DM_ + h * HD_ + ni * 16 + l16] =
          f2b(oacc[ni][j]);
}

// ---------------- host launch ----------------
extern "C" void kernel_launch(void* const* d_in, const int* in_sizes, int n_in,
                              void* d_out, int out_size, void* d_ws, size_t ws_size,
                              hipStream_t stream) {
  const float* x         = (const float*)d_in[0];
  const float* Wq_down   = (const float*)d_in[1];
  const float* q_norm_w  = (const float*)d_in[2];
  const float* Wq_up     = (const float*)d_in[3];
  const float* Wq_rope   = (const float*)d_in[4];
  const float* Wkv_down  = (const float*)d_in[5];
  const float* kv_norm_w = (const float*)d_in[6];
  const float* Wk_up     = (const float*)d_in[7];
  const float* Wv_up     = (const float*)d_in[8];
  const float* Wk_rope   = (const float*)d_in[9];
  const float* Wout      = (const float*)d_in[10];

  float* out0 = (float*)d_out;
  float* attn = out0 + (size_t)B_ * S_ * DM_;

  char* ws = (char*)d_ws;
  size_t off = 0;
  auto alloc = [&](size_t bytes) -> void* {
    void* p = ws + off;
    off += (bytes + 255) & ~(size_t)255;
    return p;
  };

  unsigned short* xb     = (unsigned short*)alloc((size_t)NTOK * DM_ * 2);
  unsigned short* WdT    = (unsigned short*)alloc((size_t)(DQL_ + DKVL_) * DM_ * 2);
  unsigned short* WrT    = (unsigned short*)alloc((size_t)DM_ * DM_ * 2);
  unsigned short* WqupT  = (unsigned short*)alloc((size_t)DM_ * DQL_ * 2);
  unsigned short* WkvupT = (unsigned short*)alloc((size_t)(2 * DM_) * DKVL_ * 2);
  unsigned short* WoutT  = (unsigned short*)alloc((size_t)DM_ * DM_ * 2);
  float* cdown           = (float*)alloc((size_t)NTOK * (DQL_ + DKVL_) * 4);
  unsigned short* cqb    = (unsigned short*)alloc((size_t)NTOK * DQL_ * 2);
  unsigned short* ckvb   = (unsigned short*)alloc((size_t)NTOK * DKVL_ * 2);
  unsigned short* Qcat   = (unsigned short*)alloc((size_t)B_ * H_ * S_ * CATD * 2);
  unsigned short* Kcat   = (unsigned short*)alloc((size_t)B_ * H_ * S_ * CATD * 2);
  unsigned short* VTb    = (unsigned short*)alloc((size_t)B_ * H_ * HD_ * S_ * 2);
  unsigned short* ctxb   = (unsigned short*)alloc((size_t)NTOK * DM_ * 2);
  float2* csT            = (float2*)alloc((size_t)S_ * 32 * sizeof(float2));

  if (off > ws_size) return;

  const float qsc = 0.07216878364870323f;    // 192^-0.5 folded into Wq_up / Wq_rope

  k_rope_tab<<<128, 256, 0, stream>>>(csT);
  k_f2b<<<(NTOK * DM_ / 4 + 255) / 256, 256, 0, stream>>>(x, xb, NTOK * DM_ / 4);

  TD8 td;
  int blk0 = 0;
  auto setd = [&](int i, const float* in, unsigned short* out, int R, int C, float sc) {
    td.d[i] = TD{in, out, R, C, blk0, sc};
    blk0 += (R >> 6) * (C >> 6);
  };
  setd(0, Wq_down,  WdT,                        DM_,  DQL_,  1.0f);
  setd(1, Wkv_down, WdT + (size_t)DQL_ * DM_,   DM_,  DKVL_, 1.0f);
  setd(2, Wq_rope,  WrT,                        DM_,  1024,  qsc);
  setd(3, Wk_rope,  WrT + (size_t)1024 * DM_,   DM_,  1024,  1.0f);
  setd(4, Wq_up,    WqupT,                      DQL_, DM_,   qsc);
  setd(5, Wk_up,    WkvupT,                     DKVL_, DM_,  1.0f);
  setd(6, Wv_up,    WkvupT + (size_t)DM_ * DKVL_, DKVL_, DM_, 1.0f);
  setd(7, Wout,     WoutT,                      DM_,  DM_,   1.0f);
  k_transpose_all<<<blk0, 256, 0, stream>>>(td);

  k_proj_a<<<368, 512, 0, stream>>>(xb, WdT, WrT, cdown, Qcat, Kcat, csT);
  k_rmsnorm<<<NTOK, 64, 0, stream>>>(cdown,        DQL_ + DKVL_, q_norm_w,  cqb,  DQL_);
  k_rmsnorm<<<NTOK, 64, 0, stream>>>(cdown + DQL_, DQL_ + DKVL_, kv_norm_w, ckvb, DKVL_);

  k_proj_b<<<768, 512, 0, stream>>>(cqb, ckvb, WqupT, WkvupT, Qcat, Kcat, VTb);

  k_attn3<<<256, 512, 0, stream>>>(Qcat, Kcat, VTb, attn, ctxb);

  k_gemm2<<<dim3(NTOK / 128, DM_ / 128), 512, 0, stream>>>(ctxb, WoutT, out0, NTOK, DM_, DM_);
}

// Round 7
// 181.097 us; speedup vs baseline: 2.8473x; 1.1660x over previous
//
#include <hip/hip_runtime.h>

#define B_    2
#define S_    1024
#define DM_   2048
#define H_    16
#define HD_   128
#define RD_   64
#define DQL_  384
#define DKVL_ 512
#define NTOK  (B_*S_)
#define CATD  (HD_+RD_)
#define LDSA  (128*64)
#define LDSB  (64*64)

typedef float f32x4 __attribute__((ext_vector_type(4)));
typedef short s16x8 __attribute__((ext_vector_type(8)));
typedef unsigned int u32;

__device__ __forceinline__ unsigned short f2b(float f) {   // fp32 -> bf16 RNE
  u32 u = __float_as_uint(f);
  u = (u + 0x7FFFu + ((u >> 16) & 1u)) >> 16;
  return (unsigned short)u;
}
__device__ __forceinline__ f32x4 mfma16(s16x8 a, s16x8 b, f32x4 c) {
  return __builtin_amdgcn_mfma_f32_16x16x32_bf16(a, b, c, 0, 0, 0);
}
__device__ __forceinline__ void gl_lds16(const void* g, void* l) {
  __builtin_amdgcn_global_load_lds((const __attribute__((address_space(1))) u32*)g,
                                   (__attribute__((address_space(3))) u32*)l, 16, 0, 0);
}

// ---- 256-thread 2-phase prefetch GEMM core: acc += A(128xK) @ Bt(64xK)^T ----
// 4 waves (2Mx2N), wave tile 64x32. BK=64 dbuf, 32KB LDS. XOR-swizzle via
// pre-swizzled global source (linear dest) + matching swizzled read.
__device__ __forceinline__ void gemm_core(const unsigned short* __restrict__ Ag,
                                          const unsigned short* __restrict__ Bg,
                                          int K,
                                          unsigned short (&As)[2][LDSA],
                                          unsigned short (&Bs)[2][LDSB],
                                          f32x4 (&acc)[4][2]) {
  const int tid = threadIdx.x;
  const int wave = tid >> 6, lane = tid & 63;
  const int wr = (wave >> 1) * 64, wc = (wave & 1) * 32;
  const int l16 = lane & 15, kg = lane >> 4;
  int sra[4], sca[4], srb[2], scb[2];
#pragma unroll
  for (int i = 0; i < 4; ++i) {
    const int g = i * 256 + tid;
    sra[i] = g >> 3;
    sca[i] = ((g & 7) ^ (sra[i] & 7)) * 8;
  }
#pragma unroll
  for (int i = 0; i < 2; ++i) {
    const int g = i * 256 + tid;
    srb[i] = g >> 3;
    scb[i] = ((g & 7) ^ (srb[i] & 7)) * 8;
  }
  auto STAGE = [&](int b, int k0) {
#pragma unroll
    for (int i = 0; i < 4; ++i)
      gl_lds16(Ag + (size_t)sra[i] * K + k0 + sca[i], (void*)&As[b][(i * 256 + tid) * 8]);
#pragma unroll
    for (int i = 0; i < 2; ++i)
      gl_lds16(Bg + (size_t)srb[i] * K + k0 + scb[i], (void*)&Bs[b][(i * 256 + tid) * 8]);
  };
  STAGE(0, 0);
  int cur = 0;
  for (int k0 = 0; k0 < K; k0 += 64) {
    __syncthreads();
    if (k0 + 64 < K) STAGE(cur ^ 1, k0 + 64);
#pragma unroll
    for (int kk = 0; kk < 2; ++kk) {
      const int sl = ((kk * 4 + kg) ^ (l16 & 7)) * 8;
      s16x8 af[4], bf2[2];
#pragma unroll
      for (int i = 0; i < 4; ++i)
        af[i] = *reinterpret_cast<const s16x8*>(&As[cur][(wr + i * 16 + l16) * 64 + sl]);
#pragma unroll
      for (int i = 0; i < 2; ++i)
        bf2[i] = *reinterpret_cast<const s16x8*>(&Bs[cur][(wc + i * 16 + l16) * 64 + sl]);
#pragma unroll
      for (int mi = 0; mi < 4; ++mi)
#pragma unroll
        for (int ni = 0; ni < 2; ++ni)
          acc[mi][ni] = mfma16(af[mi], bf2[ni], acc[mi][ni]);
    }
    cur ^= 1;
  }
}

// ---------------- prep: rope table + weight transposes + x f2b, one launch ----
struct TD { const float* in; unsigned short* out; int R, C, blk0; float scale; };
struct TD8 { TD d[8]; };
// blocks: [0,128) rope tab ; [128, 3328) transposes ; [3328, 7424) f2b
__global__ __launch_bounds__(256) void k_prep(TD8 descs, float2* __restrict__ csT,
                                              const float* __restrict__ x,
                                              unsigned short* __restrict__ xb) {
  __shared__ float tile[64][65];
  const int bid = blockIdx.x;
  const int t = threadIdx.x;
  if (bid < 128) {
    const int i = bid * 256 + t;
    const int s = i >> 5, p = i & 31;
    const float freq = powf(10000.0f, -(float)p / 32.0f);
    float sn, cs;
    sincosf((float)s * freq, &sn, &cs);
    csT[i] = make_float2(cs, sn);
    return;
  }
  if (bid >= 3328) {
    const int i = (bid - 3328) * 256 + t;
    const float4 v = reinterpret_cast<const float4*>(x)[i];
    ushort4 o;
    o.x = f2b(v.x); o.y = f2b(v.y); o.z = f2b(v.z); o.w = f2b(v.w);
    reinterpret_cast<ushort4*>(xb)[i] = o;
    return;
  }
  int di = 0;
#pragma unroll
  for (int i = 1; i < 8; ++i) if (bid >= descs.d[i].blk0) di = i;
  const TD dd = descs.d[di];
  const int local = bid - dd.blk0;
  const int tiles_r = dd.R >> 6;
  const int tr_ = local % tiles_r, tc_ = local / tiles_r;
  const int r0 = tr_ * 64, c0 = tc_ * 64;
  const int tr = t >> 4, tc4 = (t & 15) * 4;
#pragma unroll
  for (int i = 0; i < 4; ++i) {
    const int rr = tr + i * 16;
    const float4 v = *reinterpret_cast<const float4*>(dd.in + (size_t)(r0 + rr) * dd.C + c0 + tc4);
    tile[rr][tc4 + 0] = v.x; tile[rr][tc4 + 1] = v.y;
    tile[rr][tc4 + 2] = v.z; tile[rr][tc4 + 3] = v.w;
  }
  __syncthreads();
#pragma unroll
  for (int i = 0; i < 4; ++i) {
    const int oc = tr + i * 16;
    ushort4 o;
    o.x = f2b(tile[tc4 + 0][oc] * dd.scale); o.y = f2b(tile[tc4 + 1][oc] * dd.scale);
    o.z = f2b(tile[tc4 + 2][oc] * dd.scale); o.w = f2b(tile[tc4 + 3][oc] * dd.scale);
    *reinterpret_cast<ushort4*>(dd.out + (size_t)(c0 + oc) * dd.R + r0 + tc4) = o;
  }
}

// ---------------- Wout GEMM: 512 blocks (128x64 tiles) ----------------
__global__ __launch_bounds__(256, 4) void k_gemm2(const unsigned short* __restrict__ A,
                                                  const unsigned short* __restrict__ Bt,
                                                  float* __restrict__ C,
                                                  int M, int N, int K) {
  __shared__ unsigned short As[2][LDSA];
  __shared__ unsigned short Bs[2][LDSB];
  const int mt = M >> 7;
  const int nwg = mt * (N >> 6);
  int id = blockIdx.x;
  id = (id & 7) * (nwg >> 3) + (id >> 3);
  const int tm = (id % mt) * 128;
  const int tn = (id / mt) * 64;
  const int tid = threadIdx.x;
  const int wave = tid >> 6, lane = tid & 63;
  const int wr = (wave >> 1) * 64, wc = (wave & 1) * 32;
  const int l16 = lane & 15, kg = lane >> 4;

  f32x4 acc[4][2] = {};
  gemm_core(A + (size_t)tm * K, Bt + (size_t)tn * K, K, As, Bs, acc);

#pragma unroll
  for (int mi = 0; mi < 4; ++mi)
#pragma unroll
    for (int ni = 0; ni < 2; ++ni) {
      const int rr = tm + wr + mi * 16 + kg * 4;
      const int cc = tn + wc + ni * 16 + l16;
#pragma unroll
      for (int j = 0; j < 4; ++j)
        C[(size_t)(rr + j) * N + cc] = acc[mi][ni][j];
    }
}

// ---------------- launch 1: A=xb. down(N=896)->cdown ; rope(N=2048)->Qcat/Kcat --
// 736 blocks = 224 down + 512 rope
__global__ __launch_bounds__(256, 4) void k_proj_a(const unsigned short* __restrict__ xb,
                                                   const unsigned short* __restrict__ WdT,
                                                   const unsigned short* __restrict__ WrT,
                                                   float* __restrict__ cdown,
                                                   unsigned short* __restrict__ Qcat,
                                                   unsigned short* __restrict__ Kcat,
                                                   const float2* __restrict__ csT) {
  __shared__ unsigned short As[2][LDSA];
  __shared__ unsigned short Bs[2][LDSB];
  int id = blockIdx.x;
  id = (id & 7) * 92 + (id >> 3);
  const bool down = id < 224;
  int gm, tn; const unsigned short* Bt;
  if (down) { gm = id % 16; tn = (id / 16) * 64; Bt = WdT; }
  else { const int i2 = id - 224; gm = i2 % 16; tn = (i2 / 16) * 64; Bt = WrT; }
  const int tm = gm * 128;

  const int tid = threadIdx.x;
  const int wave = tid >> 6, lane = tid & 63;
  const int wr = (wave >> 1) * 64, wc = (wave & 1) * 32;
  const int l16 = lane & 15, kg = lane >> 4;

  f32x4 acc[4][2] = {};
  gemm_core(xb + (size_t)tm * DM_, Bt + (size_t)tn * DM_, DM_, As, Bs, acc);

  if (down) {
#pragma unroll
    for (int mi = 0; mi < 4; ++mi)
#pragma unroll
      for (int ni = 0; ni < 2; ++ni) {
        const int rr = tm + wr + mi * 16 + kg * 4;
        const int cc = tn + wc + ni * 16 + l16;
#pragma unroll
        for (int j = 0; j < 4; ++j)
          cdown[(size_t)(rr + j) * (DQL_ + DKVL_) + cc] = acc[mi][ni][j];
      }
  } else {
#pragma unroll
    for (int mi = 0; mi < 4; ++mi)
#pragma unroll
      for (int ni = 0; ni < 2; ++ni) {
        const int col = tn + wc + ni * 16 + l16;
        unsigned short* dst = (col < 1024) ? Qcat : Kcat;
        const int c1 = col & 1023;
        const int hh = c1 >> 6, dd2 = c1 & 63, p = dd2 >> 1, odd = dd2 & 1;
        const int row0 = tm + wr + mi * 16 + kg * 4;
#pragma unroll
        for (int j = 0; j < 4; ++j) {
          const float own = acc[mi][ni][j];
          const float prt = __shfl_xor(own, 1, 64);
          const int tok = row0 + j, b = tok >> 10, s = tok & 1023;
          const float2 cs = csT[s * 32 + p];
          const float o = odd ? (prt * cs.y + own * cs.x) : (own * cs.x - prt * cs.y);
          dst[((size_t)(b * H_ + hh) * S_ + s) * CATD + HD_ + dd2] = f2b(o);
        }
      }
  }
}

// ---------------- launch 2: q-up + kv-up -> Qcat/Kcat/VT. 1536 blocks ----------
__global__ __launch_bounds__(256, 4) void k_proj_b(const unsigned short* __restrict__ cqb,
                                                   const unsigned short* __restrict__ ckvb,
                                                   const unsigned short* __restrict__ WqupT,
                                                   const unsigned short* __restrict__ WkvupT,
                                                   unsigned short* __restrict__ Qcat,
                                                   unsigned short* __restrict__ Kcat,
                                                   unsigned short* __restrict__ VTb) {
  __shared__ unsigned short As[2][LDSA];
  __shared__ unsigned short Bs[2][LDSB];
  int id = blockIdx.x;
  id = (id & 7) * 192 + (id >> 3);
  const bool qgrp = id < 512;
  int gm, tn, K; const unsigned short* Bt; const unsigned short* A;
  if (qgrp) { gm = id & 15; tn = (id >> 4) * 64; Bt = WqupT; A = cqb; K = DQL_; }
  else { const int i2 = id - 512; gm = i2 & 15; tn = (i2 >> 4) * 64; Bt = WkvupT; A = ckvb; K = DKVL_; }
  const int tm = gm * 128;

  const int tid = threadIdx.x;
  const int wave = tid >> 6, lane = tid & 63;
  const int wr = (wave >> 1) * 64, wc = (wave & 1) * 32;
  const int l16 = lane & 15, kg = lane >> 4;

  f32x4 acc[4][2] = {};
  gemm_core(A + (size_t)tm * K, Bt + (size_t)tn * K, K, As, Bs, acc);

#pragma unroll
  for (int mi = 0; mi < 4; ++mi)
#pragma unroll
    for (int ni = 0; ni < 2; ++ni) {
      const int col = tn + wc + ni * 16 + l16;
      const int row0 = tm + wr + mi * 16 + kg * 4;
      if (qgrp || col < 2048) {
        unsigned short* dst = qgrp ? Qcat : Kcat;
        const int hh = (col & 2047) >> 7, d = col & 127;
#pragma unroll
        for (int j = 0; j < 4; ++j) {
          const int tok = row0 + j, b = tok >> 10, s = tok & 1023;
          dst[((size_t)(b * H_ + hh) * S_ + s) * CATD + d] = f2b(acc[mi][ni][j]);
        }
      } else {
        const int m2 = col - 2048;
        const int hh = m2 >> 7, d = m2 & 127;
        const int b = row0 >> 10, s0 = row0 & 1023;
        ushort4 o;
        o.x = f2b(acc[mi][ni][0]); o.y = f2b(acc[mi][ni][1]);
        o.z = f2b(acc[mi][ni][2]); o.w = f2b(acc[mi][ni][3]);
        *reinterpret_cast<ushort4*>(&VTb[((size_t)(b * H_ + hh) * HD_ + d) * S_ + s0]) = o;
      }
    }
}

// ---------------- RMSNorm, q+kv in one launch (4096 blocks) ----------------
__global__ __launch_bounds__(64) void k_rmsnorm2(const float* __restrict__ cdown,
                                                 const float* __restrict__ qw,
                                                 const float* __restrict__ kvw,
                                                 unsigned short* __restrict__ cqb,
                                                 unsigned short* __restrict__ ckvb) {
  const int row = blockIdx.x;
  const bool isq = row < NTOK;
  const int r = isq ? row : row - NTOK;
  const int D = isq ? DQL_ : DKVL_;
  const float* x = cdown + (size_t)r * (DQL_ + DKVL_) + (isq ? 0 : DQL_);
  const float* w = isq ? qw : kvw;
  unsigned short* out = (isq ? cqb : ckvb) + (size_t)r * D;
  float ss = 0.f;
  for (int i = threadIdx.x; i < D; i += 64) { const float v = x[i]; ss = fmaf(v, v, ss); }
#pragma unroll
  for (int off = 32; off; off >>= 1) ss += __shfl_xor(ss, off, 64);
  const float rr = rsqrtf(ss / (float)D + 1e-6f);
  for (int i = threadIdx.x; i < D; i += 64) out[i] = f2b(x[i] * rr * w[i]);
}

// ---------------- fused attention: 512 blocks x 256 thr, 2 blocks/CU ----------
#define KVB 64
__global__ __launch_bounds__(256, 2) void k_attn3(const unsigned short* __restrict__ Qcat,
                                                  const unsigned short* __restrict__ Kcat,
                                                  const unsigned short* __restrict__ VT,
                                                  float* __restrict__ attn_out,
                                                  unsigned short* __restrict__ ctx) {
  __shared__ unsigned short Ks[2][KVB * 192];   // 48 KB
  __shared__ unsigned short Vs[128 * 64];       // 16 KB
  __shared__ unsigned short Pl[4][16 * 64];     // 8 KB
  const int d0 = blockIdx.x;
  const int xcd = d0 & 7, i0 = d0 >> 3;
  const int bh = xcd + ((i0 >> 4) << 3);
  const int qc = i0 & 15;
  const int b = bh >> 4, h = bh & 15;

  const int tid = threadIdx.x, wave = tid >> 6, lane = tid & 63;
  const int l16 = lane & 15, kg = lane >> 4;
  const int qw = qc * 64 + wave * 16;

  const unsigned short* Qb = Qcat + ((size_t)bh * S_ + qw) * CATD;
  s16x8 qf[6];
#pragma unroll
  for (int ks = 0; ks < 6; ++ks)
    qf[ks] = *reinterpret_cast<const s16x8*>(Qb + (size_t)l16 * CATD + ks * 32 + kg * 8);

  int srk[6], sck[6];
#pragma unroll
  for (int j = 0; j < 6; ++j) {
    const int s = j * 256 + tid;
    srk[j] = s / 24;
    sck[j] = ((s % 24) ^ (srk[j] & 7)) * 8;
  }
  const unsigned short* Kb = Kcat + (size_t)bh * S_ * CATD;
  auto STAGE_K = [&](int bb, int ch) {
    const unsigned short* Kc = Kb + (size_t)ch * KVB * CATD;
#pragma unroll
    for (int j = 0; j < 6; ++j)
      gl_lds16(Kc + (size_t)srk[j] * CATD + sck[j], (void*)&Ks[bb][(j * 256 + tid) * 8]);
  };

  const unsigned short* Vb = VT + (size_t)bh * HD_ * S_;
  int srv[4], scv[4];
#pragma unroll
  for (int i = 0; i < 4; ++i) {
    const int g = i * 256 + tid;
    srv[i] = g >> 3;
    scv[i] = ((g & 7) ^ (srv[i] & 7)) * 8;
  }
  auto STAGE_V = [&](int ch) {
#pragma unroll
    for (int i = 0; i < 4; ++i)
      gl_lds16(Vb + (size_t)srv[i] * S_ + ch * KVB + scv[i], (void*)&Vs[(i * 256 + tid) * 8]);
  };

  f32x4 oacc[8] = {};
  float mx = -1e30f, sm = 0.f, rl = 0.f;

  STAGE_K(0, 0);
  int cur = 0;
  for (int g = 0; g < 32; ++g) {
    __syncthreads();                        // Ks[cur] ready; Vs/Pl consumed
    const int ch = g & 15;
    const bool p2 = g >= 16;
    if (p2) STAGE_V(ch);                    // 4 gl_lds; gated by counted vmcnt below
    if (g < 31) STAGE_K(cur ^ 1, (g + 1) & 15);   // 6 gl_lds stay in flight

    f32x4 acc[4] = {};
#pragma unroll
    for (int ni = 0; ni < 4; ++ni) {
      const int row = ni * 16 + l16;
#pragma unroll
      for (int ks = 0; ks < 6; ++ks) {
        const int slot = (ks * 4 + kg) ^ (l16 & 7);
        const s16x8 af = *reinterpret_cast<const s16x8*>(&Ks[cur][row * 192 + slot * 8]);
        acc[ni] = mfma16(af, qf[ks], acc[ni]);
      }
    }

    if (!p2) {
      float cm = -1e30f;
#pragma unroll
      for (int ni = 0; ni < 4; ++ni)
#pragma unroll
        for (int j = 0; j < 4; ++j) cm = fmaxf(cm, acc[ni][j]);
      const float nm = fmaxf(mx, cm);
      sm *= __expf(mx - nm);
#pragma unroll
      for (int ni = 0; ni < 4; ++ni)
#pragma unroll
        for (int j = 0; j < 4; ++j) sm += __expf(acc[ni][j] - nm);
      mx = nm;
      if (g == 15) {                        // combine the 4 kg-group k-subsets
#pragma unroll
        for (int off = 16; off < 64; off <<= 1) {
          const float om = __shfl_xor(mx, off, 64);
          const float os = __shfl_xor(sm, off, 64);
          const float nm2 = fmaxf(mx, om);
          sm = sm * __expf(mx - nm2) + os * __expf(om - nm2);
          mx = nm2;
        }
        rl = 1.0f / sm;
      }
    } else {
      // V-ready gate: outstanding = 4(V) + 6(K-prefetch); keep K in flight
      if (g < 31) asm volatile("s_waitcnt vmcnt(6)" ::: "memory");
      else        asm volatile("s_waitcnt vmcnt(0)" ::: "memory");
      __builtin_amdgcn_s_barrier();
      __builtin_amdgcn_sched_barrier(0);

      float* Ao = attn_out + ((size_t)bh * S_ + qw + l16) * S_ + ch * KVB;
      unsigned short* Pw = &Pl[wave][0];
#pragma unroll
      for (int ni = 0; ni < 4; ++ni) {
        float4 w4;
        w4.x = __expf(acc[ni][0] - mx) * rl;
        w4.y = __expf(acc[ni][1] - mx) * rl;
        w4.z = __expf(acc[ni][2] - mx) * rl;
        w4.w = __expf(acc[ni][3] - mx) * rl;
        *reinterpret_cast<float4*>(Ao + ni * 16 + kg * 4) = w4;
        ushort4 pb;
        pb.x = f2b(w4.x); pb.y = f2b(w4.y); pb.z = f2b(w4.z); pb.w = f2b(w4.w);
        *reinterpret_cast<ushort4*>(&Pw[l16 * 64 + (((ni * 4 + kg) ^ l16) * 4)]) = pb;
      }
#pragma unroll
      for (int kk = 0; kk < 2; ++kk) {
        const short4 lo = *reinterpret_cast<const short4*>(&Pw[l16 * 64 + (((kk * 8 + kg * 2 + 0) ^ l16) * 4)]);
        const short4 hi = *reinterpret_cast<const short4*>(&Pw[l16 * 64 + (((kk * 8 + kg * 2 + 1) ^ l16) * 4)]);
        s16x8 pa;
        pa[0] = lo.x; pa[1] = lo.y; pa[2] = lo.z; pa[3] = lo.w;
        pa[4] = hi.x; pa[5] = hi.y; pa[6] = hi.z; pa[7] = hi.w;
#pragma unroll
        for (int ni = 0; ni < 8; ++ni) {
          const int row = ni * 16 + l16;
          const s16x8 vf = *reinterpret_cast<const s16x8*>(
              &Vs[row * 64 + (((kk * 4 + kg) ^ (l16 & 7)) * 8)]);
          oacc[ni] = mfma16(pa, vf, oacc[ni]);
        }
      }
    }
    cur ^= 1;
  }

#pragma unroll
  for (int ni = 0; ni < 8; ++ni)
#pragma unroll
    for (int j = 0; j < 4; ++j)
      ctx[((size_t)(b * S_ + qw + kg * 4 + j)) * DM_ + h * HD_ + ni * 16 + l16] =
          f2b(oacc[ni][j]);
}

// ---------------- host launch ----------------
extern "C" void kernel_launch(void* const* d_in, const int* in_sizes, int n_in,
                              void* d_out, int out_size, void* d_ws, size_t ws_size,
                              hipStream_t stream) {
  const float* x         = (const float*)d_in[0];
  const float* Wq_down   = (const float*)d_in[1];
  const float* q_norm_w  = (const float*)d_in[2];
  const float* Wq_up     = (const float*)d_in[3];
  const float* Wq_rope   = (const float*)d_in[4];
  const float* Wkv_down  = (const float*)d_in[5];
  const float* kv_norm_w = (const float*)d_in[6];
  const float* Wk_up     = (const float*)d_in[7];
  const float* Wv_up     = (const float*)d_in[8];
  const float* Wk_rope   = (const float*)d_in[9];
  const float* Wout      = (const float*)d_in[10];

  float* out0 = (float*)d_out;
  float* attn = out0 + (size_t)B_ * S_ * DM_;

  char* ws = (char*)d_ws;
  size_t off = 0;
  auto alloc = [&](size_t bytes) -> void* {
    void* p = ws + off;
    off += (bytes + 255) & ~(size_t)255;
    return p;
  };

  unsigned short* xb     = (unsigned short*)alloc((size_t)NTOK * DM_ * 2);
  unsigned short* WdT    = (unsigned short*)alloc((size_t)(DQL_ + DKVL_) * DM_ * 2);
  unsigned short* WrT    = (unsigned short*)alloc((size_t)DM_ * DM_ * 2);
  unsigned short* WqupT  = (unsigned short*)alloc((size_t)DM_ * DQL_ * 2);
  unsigned short* WkvupT = (unsigned short*)alloc((size_t)(2 * DM_) * DKVL_ * 2);
  unsigned short* WoutT  = (unsigned short*)alloc((size_t)DM_ * DM_ * 2);
  float* cdown           = (float*)alloc((size_t)NTOK * (DQL_ + DKVL_) * 4);
  unsigned short* cqb    = (unsigned short*)alloc((size_t)NTOK * DQL_ * 2);
  unsigned short* ckvb   = (unsigned short*)alloc((size_t)NTOK * DKVL_ * 2);
  unsigned short* Qcat   = (unsigned short*)alloc((size_t)B_ * H_ * S_ * CATD * 2);
  unsigned short* Kcat   = (unsigned short*)alloc((size_t)B_ * H_ * S_ * CATD * 2);
  unsigned short* VTb    = (unsigned short*)alloc((size_t)B_ * H_ * HD_ * S_ * 2);
  unsigned short* ctxb   = (unsigned short*)alloc((size_t)NTOK * DM_ * 2);
  float2* csT            = (float2*)alloc((size_t)S_ * 32 * sizeof(float2));

  if (off > ws_size) return;

  const float qsc = 0.07216878364870323f;    // 192^-0.5 folded into Wq_up / Wq_rope

  TD8 td;
  int blk0 = 128;
  auto setd = [&](int i, const float* in, unsigned short* out, int R, int C, float sc) {
    td.d[i] = TD{in, out, R, C, blk0, sc};
    blk0 += (R >> 6) * (C >> 6);
  };
  setd(0, Wq_down,  WdT,                        DM_,  DQL_,  1.0f);
  setd(1, Wkv_down, WdT + (size_t)DQL_ * DM_,   DM_,  DKVL_, 1.0f);
  setd(2, Wq_rope,  WrT,                        DM_,  1024,  qsc);
  setd(3, Wk_rope,  WrT + (size_t)1024 * DM_,   DM_,  1024,  1.0f);
  setd(4, Wq_up,    WqupT,                      DQL_, DM_,   qsc);
  setd(5, Wk_up,    WkvupT,                     DKVL_, DM_,  1.0f);
  setd(6, Wv_up,    WkvupT + (size_t)DM_ * DKVL_, DKVL_, DM_, 1.0f);
  setd(7, Wout,     WoutT,                      DM_,  DM_,   1.0f);
  // blk0 == 3328 here; f2b occupies [3328, 3328+4096)
  k_prep<<<3328 + (NTOK * DM_ / 4) / 256, 256, 0, stream>>>(td, csT, x, xb);

  k_proj_a<<<736, 256, 0, stream>>>(xb, WdT, WrT, cdown, Qcat, Kcat, csT);
  k_rmsnorm2<<<2 * NTOK, 64, 0, stream>>>(cdown, q_norm_w, kv_norm_w, cqb, ckvb);
  k_proj_b<<<1536, 256, 0, stream>>>(cqb, ckvb, WqupT, WkvupT, Qcat, Kcat, VTb);

  k_attn3<<<512, 256, 0, stream>>>(Qcat, Kcat, VTb, attn, ctxb);

  k_gemm2<<<512, 256, 0, stream>>>(ctxb, WoutT, out0, NTOK, DM_, DM_);
}